// Round 11
// baseline (276.698 us; speedup 1.0000x reference)
//
#include <hip/hip_runtime.h>
#include <hip/hip_bf16.h>
#include <math.h>

#define D 128
#define AGG_THREADS 128
#define CHUNK 512
#define BSHIFT 6                 // 64 dst nodes per bucket (fast path)
#define BK 64                    // 1 << BSHIFT
#define MAXB 2048                // max buckets (LDS arrays in partition)
#define MAXWG 512                // max partition WGs (LDS arrays in fused kernel)
#define PCHUNK 4096              // edges per partition WG
#define PE 16                    // PCHUNK / 256
#define EBUF_CAP 1792            // LDS staging cap in fused kernel (mean 1024, +24 sigma)
#define PR 2048                  // spill region stride per bucket (slow path only)

// ---------- helpers ----------
__device__ __forceinline__ unsigned short f2bf(float f) {
    union { float f; unsigned int u; } c; c.f = f;
    unsigned int u = c.u;
    unsigned int r = (u + 0x7FFFu + ((u >> 16) & 1u)) >> 16;  // RNE
    return (unsigned short)r;
}
__device__ __forceinline__ void unpack2(unsigned int w, float& lo, float& hi) {
    union { unsigned int u; float f; } c;
    c.u = w << 16;          lo = c.f;
    c.u = w & 0xFFFF0000u;  hi = c.f;
}

// 4-wave parallel exclusive scan over arr[0..n) in LDS, result into outp[0..n).
__device__ __forceinline__ void scan4w(const int* __restrict__ arr, int* __restrict__ outp,
                                       int n, int tid, int* wsum4) {
    int wv = tid >> 6, lane = tid & 63;
    int nchunk = (n + 63) >> 6;
    int cpw = (nchunk + 3) >> 2;
    int c0 = wv * cpw, c1 = min(nchunk, c0 + cpw);
    int carry = 0;
    for (int c = c0; c < c1; ++c) {
        int i = (c << 6) + lane;
        int v = (i < n) ? arr[i] : 0;
        int x = v;
        #pragma unroll
        for (int off = 1; off < 64; off <<= 1) {
            int t = __shfl_up(x, off, 64);
            if (lane >= off) x += t;
        }
        if (i < n) outp[i] = x - v + carry;
        carry += __shfl(x, 63, 64);
    }
    if (lane == 0) wsum4[wv] = carry;
    __syncthreads();
    int wbase = 0;
    for (int u = 0; u < wv; ++u) wbase += wsum4[u];
    if (wbase) {
        for (int c = c0; c < c1; ++c) {
            int i = (c << 6) + lane;
            if (i < n) outp[i] += wbase;
        }
    }
    __syncthreads();
}

// ---------- prep: el/er dots + bf16 copy of feat_src; float4 loads ----------
__global__ void prep_kernel(const float* __restrict__ feat_src,
                            const float* __restrict__ feat_dst,
                            const float* __restrict__ attn_l,
                            const float* __restrict__ attn_r,
                            float* __restrict__ el, float* __restrict__ er,
                            unsigned short* __restrict__ feat_bf, int store_bf,
                            int Ns, int Nd) {
    int half = threadIdx.x >> 5;           // 0..7 (8 rows per 256-thread block)
    int lane = threadIdx.x & 31;
    int node = blockIdx.x * 8 + half;
    if (node >= Ns + Nd) return;
    bool is_src = node < Ns;
    const float* feat = is_src ? feat_src + (size_t)node * D
                               : feat_dst + (size_t)(node - Ns) * D;
    const float* attn = is_src ? attn_l : attn_r;
    float4 a = ((const float4*)attn)[lane];
    float4 v = ((const float4*)feat)[lane];
    if (is_src && store_bf) {
        ushort4 h; h.x = f2bf(v.x); h.y = f2bf(v.y); h.z = f2bf(v.z); h.w = f2bf(v.w);
        ((ushort4*)(feat_bf + (size_t)node * D))[lane] = h;
    }
    float s = v.x * a.x + v.y * a.y + v.z * a.z + v.w * a.w;
    #pragma unroll
    for (int off = 16; off > 0; off >>= 1)
        s += __shfl_xor(s, off, 64);       // xor<=16 stays within each 32-lane half
    if (lane == 0) {
        if (is_src) el[node] = s;
        else        er[node - Ns] = s;
    }
}

// ---------- partition: WG-local counting sort by bucket, ZERO global atomics ----------
// Writes interleaved per-chunk table tab[w][b] = (cnt, loc)  (coalesced along b).
__global__ void partition_kernel(const int* __restrict__ src, const int* __restrict__ dst,
                                 int E, int nbk,
                                 uint2* __restrict__ bins,
                                 int2* __restrict__ tab) {
    __shared__ int hist[MAXB];
    __shared__ int lstart[MAXB];
    __shared__ int cursor[MAXB];
    __shared__ uint2 sbuf[PCHUNK];         // 32 KB
    __shared__ int wsum4[4];
    int w = blockIdx.x, tid = threadIdx.x;
    int e0 = w * PCHUNK;
    int e1 = min(E, e0 + PCHUNK);
    int n = e1 - e0;

    for (int i = tid; i < nbk; i += 256) hist[i] = 0;
    __syncthreads();

    int es[PE], ed[PE];
    #pragma unroll
    for (int k = 0; k < PE; ++k) {
        int idx = e0 + k * 256 + tid;
        if (idx < e1) {
            es[k] = src[idx];
            ed[k] = dst[idx];
            atomicAdd(&hist[ed[k] >> BSHIFT], 1);
        }
    }
    __syncthreads();

    // 4-wave parallel exclusive scan of hist -> lstart
    scan4w(hist, lstart, nbk, tid, wsum4);

    for (int i = tid; i < nbk; i += 256) {
        tab[(size_t)w * nbk + i] = make_int2(hist[i], lstart[i]);
        cursor[i] = 0;
    }
    __syncthreads();

    #pragma unroll
    for (int k = 0; k < PE; ++k) {
        int idx = e0 + k * 256 + tid;
        if (idx < e1) {
            int b = ed[k] >> BSHIFT;
            int r = lstart[b] + atomicAdd(&cursor[b], 1);
            sbuf[r] = make_uint2((unsigned)es[k], (unsigned)ed[k]);
        }
    }
    __syncthreads();

    uint2* obase = bins + (size_t)w * PCHUNK;
    for (int t = tid; t < n; t += 256) obase[t] = sbuf[t];   // coalesced
}

// ---------- FUSED bucket + aggregate ----------
// One 256-thread block per 64-dst bucket (~1024 edges).
// Phase A (bucket): gather this bucket's edges from bins into LDS (binary
//   search over segment starts), count per dst, wave64 scan, ranked scatter
//   of src indices into LDS sperm -- dst-sorted edge lists, never touch global.
// Phase B (aggregate): 4 waves x 16 dst each; softmax + bf16 feature gather,
//   edge lists read from LDS. Verified wave-per-dst code with perm->sperm.
// Slow path (n > EBUF_CAP, statistically unreachable): spill via global region.
__global__ void bucket_agg_kernel(const uint2* __restrict__ bins,
                                  const int2* __restrict__ tab,
                                  int nbk, int nwg,
                                  const unsigned short* __restrict__ feat_bf,
                                  const float* __restrict__ el,
                                  const float* __restrict__ er,
                                  int* __restrict__ spill,
                                  float* __restrict__ out, int Nd) {
    __shared__ uint2 ebuf[EBUF_CAP];       // 14 KB
    __shared__ int sperm[EBUF_CAP];        // 7 KB: dst-sorted src indices
    __shared__ int wcnt[MAXWG];
    __shared__ int wdst[MAXWG];
    __shared__ int sbase[MAXWG];           // 6 KB total for the 3
    __shared__ int cntB[BK];
    __shared__ int offB[BK];
    __shared__ int curB[BK];
    __shared__ int wsum4[4];

    int b = blockIdx.x, tid = threadIdx.x;
    int base = b << BSHIFT;

    // ---- Phase A ----
    for (int i = tid; i < nwg; i += 256) {
        int2 t = tab[(size_t)i * nbk + b];      // strided (proven equivalent, R9)
        wcnt[i] = t.x;
        sbase[i] = t.y;                         // loc for now
    }
    if (tid < BK) { cntB[tid] = 0; curB[tid] = 0; }
    __syncthreads();

    scan4w(wcnt, wdst, nwg, tid, wsum4);
    int n = wsum4[0] + wsum4[1] + wsum4[2] + wsum4[3];
    bool fits = (n <= EBUF_CAP);

    for (int w = tid; w < nwg; w += 256)
        sbase[w] = w * PCHUNK + sbase[w] - wdst[w];   // bins[sbase[w]+t] = edge t
    __syncthreads();

    if (fits) {
        for (int t = tid; t < n; t += 256) {
            int lo = 0, hi = nwg - 1;
            while (lo < hi) {              // last w with wdst[w] <= t
                int mid = (lo + hi + 1) >> 1;
                if (wdst[mid] <= t) lo = mid; else hi = mid - 1;
            }
            uint2 e = bins[(size_t)(sbase[lo] + t)];
            ebuf[t] = e;
            atomicAdd(&cntB[(int)e.y - base], 1);
        }
    } else {
        for (int w = tid; w < nwg; w += 256) {
            int c = wcnt[w];
            const uint2* sp = bins + (size_t)(sbase[w] + wdst[w]);
            for (int k = 0; k < c; ++k)
                atomicAdd(&cntB[(int)sp[k].y - base], 1);
        }
    }
    __syncthreads();

    // wave64 exclusive scan of the 64 per-dst counts; clamp only on spill path
    if (tid < 64) {
        int v = cntB[tid];
        int x = v;
        #pragma unroll
        for (int off = 1; off < 64; off <<= 1) {
            int t = __shfl_up(x, off, 64);
            if (tid >= off) x += t;
        }
        int myoff = x - v;
        offB[tid] = myoff;
        int c = v;
        if (!fits) c = max(0, min(c, PR - myoff));
        cntB[tid] = c;
    }
    __syncthreads();

    if (fits) {
        for (int t = tid; t < n; t += 256) {
            uint2 e = ebuf[t];
            int d = (int)e.y - base;
            int r = atomicAdd(&curB[d], 1);
            sperm[offB[d] + r] = (int)e.x;       // offB[d]+r < n <= EBUF_CAP
        }
    } else {
        size_t rbase = (size_t)b * PR;
        for (int w = tid; w < nwg; w += 256) {
            int c = wcnt[w];
            const uint2* sp = bins + (size_t)(sbase[w] + wdst[w]);
            for (int k = 0; k < c; ++k) {
                uint2 e = sp[k];
                int d = (int)e.y - base;
                int r = atomicAdd(&curB[d], 1);
                int slot = offB[d] + r;
                if (slot < PR) spill[rbase + slot] = (int)e.x;
            }
        }
    }
    __syncthreads();

    // ---- Phase B: 4 waves x 16 dst, no barriers ----
    int wid = tid >> 6, lane = tid & 63;
    int sg = lane >> 4, u = lane & 15;
    const unsigned short* fb = feat_bf + (size_t)u * 8;
    const int* gspill = spill + (size_t)b * PR;

    for (int q = 0; q < 16; ++q) {
        int d = wid * 16 + q;                  // wave-uniform
        int j = base + d;
        if (j >= Nd) break;
        int cnt = cntB[d];
        size_t orow = (size_t)j * D;
        if (cnt == 0) {
            ((float2*)(out + orow))[lane] = make_float2(0.0f, 0.0f);
            continue;
        }
        int doff = offB[d];
        float erj = er[j];
        float acc[8];
        #pragma unroll
        for (int k = 0; k < 8; ++k) acc[k] = 0.0f;

        if (cnt <= 64) {
            int s = 0; float e = -INFINITY;
            if (lane < cnt) {
                s = fits ? sperm[doff + lane] : gspill[doff + lane];
                float t = el[s] + erj;
                e = (t >= 0.0f) ? t : 0.01f * t;   // leaky_relu
            }
            float m = e;
            #pragma unroll
            for (int off = 32; off > 0; off >>= 1)
                m = fmaxf(m, __shfl_xor(m, off, 64));
            float a = (lane < cnt) ? __expf(e - m) : 0.0f;
            float den = a;
            #pragma unroll
            for (int off = 32; off > 0; off >>= 1)
                den += __shfl_xor(den, off, 64);
            a *= (1.0f / den);                      // pre-normalized weight
            int nit = (cnt + 3) >> 2;               // uniform trip count
            int it = 0;
            for (; it + 2 <= nit; it += 2) {        // 2-deep pipeline
                int t0 = sg + (it << 2);
                int t1 = t0 + 4;
                int u1 = (t1 < cnt) ? t1 : 0;
                float w0 = __shfl(a, t0, 64);
                int   s0 = __shfl(s, t0, 64);
                float w1 = __shfl(a, u1, 64);
                int   s1 = __shfl(s, u1, 64);
                bool p1 = (t1 < cnt);
                uint4 v0 = *(const uint4*)(fb + (size_t)s0 * D);
                uint4 v1 = p1 ? *(const uint4*)(fb + (size_t)s1 * D) : make_uint4(0,0,0,0);
                float f[8];
                unpack2(v0.x, f[0], f[1]); unpack2(v0.y, f[2], f[3]);
                unpack2(v0.z, f[4], f[5]); unpack2(v0.w, f[6], f[7]);
                #pragma unroll
                for (int k = 0; k < 8; ++k) acc[k] += w0 * f[k];
                if (p1) {
                    unpack2(v1.x, f[0], f[1]); unpack2(v1.y, f[2], f[3]);
                    unpack2(v1.z, f[4], f[5]); unpack2(v1.w, f[6], f[7]);
                    #pragma unroll
                    for (int k = 0; k < 8; ++k) acc[k] += w1 * f[k];
                }
            }
            if (it < nit) {                         // tail
                int t0 = sg + (it << 2);
                int u0 = (t0 < cnt) ? t0 : 0;
                float w0 = __shfl(a, u0, 64);
                int   s0 = __shfl(s, u0, 64);
                if (t0 < cnt) {
                    uint4 v0 = *(const uint4*)(fb + (size_t)s0 * D);
                    float f[8];
                    unpack2(v0.x, f[0], f[1]); unpack2(v0.y, f[2], f[3]);
                    unpack2(v0.z, f[4], f[5]); unpack2(v0.w, f[6], f[7]);
                    #pragma unroll
                    for (int k = 0; k < 8; ++k) acc[k] += w0 * f[k];
                }
            }
        } else {
            // chunked path (cnt > 64)
            float lmax = -INFINITY;
            for (int t = lane; t < cnt; t += 64) {
                int s = fits ? sperm[doff + t] : gspill[doff + t];
                float e = el[s] + erj;
                e = (e >= 0.0f) ? e : 0.01f * e;
                lmax = fmaxf(lmax, e);
            }
            float m = lmax;
            #pragma unroll
            for (int off = 32; off > 0; off >>= 1)
                m = fmaxf(m, __shfl_xor(m, off, 64));
            float lsum = 0.0f;
            for (int t = lane; t < cnt; t += 64) {
                int s = fits ? sperm[doff + t] : gspill[doff + t];
                float e = el[s] + erj;
                e = (e >= 0.0f) ? e : 0.01f * e;
                lsum += __expf(e - m);
            }
            #pragma unroll
            for (int off = 32; off > 0; off >>= 1)
                lsum += __shfl_xor(lsum, off, 64);
            float inv = 1.0f / lsum;
            for (int bb = 0; bb < cnt; bb += 64) {
                int nn = min(64, cnt - bb);
                int s = 0; float a = 0.0f;
                if (lane < nn) {
                    s = fits ? sperm[doff + bb + lane] : gspill[doff + bb + lane];
                    float e = el[s] + erj;
                    e = (e >= 0.0f) ? e : 0.01f * e;
                    a = __expf(e - m) * inv;
                }
                int nit = (nn + 3) >> 2;
                for (int it = 0; it < nit; ++it) {
                    int t = sg + (it << 2);
                    int tt = (t < nn) ? t : 0;
                    float w = __shfl(a, tt, 64);
                    int st  = __shfl(s, tt, 64);
                    if (t < nn) {
                        uint4 v = *(const uint4*)(fb + (size_t)st * D);
                        float f[8];
                        unpack2(v.x, f[0], f[1]); unpack2(v.y, f[2], f[3]);
                        unpack2(v.z, f[4], f[5]); unpack2(v.w, f[6], f[7]);
                        #pragma unroll
                        for (int k = 0; k < 8; ++k) acc[k] += w * f[k];
                    }
                }
            }
        }
        // reduce across the 4 subgroups (lane bits 4,5)
        #pragma unroll
        for (int k = 0; k < 8; ++k) {
            acc[k] += __shfl_xor(acc[k], 16, 64);
            acc[k] += __shfl_xor(acc[k], 32, 64);
        }
        if (sg == 0) {
            float* op = out + orow + (size_t)u * 8;
            ((float4*)op)[0] = make_float4(acc[0], acc[1], acc[2], acc[3]);
            ((float4*)op)[1] = make_float4(acc[4], acc[5], acc[6], acc[7]);
        }
    }
}

// ---------- block reductions (128 threads = 2 waves) for fallback aggregate ----------
__device__ __forceinline__ float block_max128(float v, float* red, int tid) {
    #pragma unroll
    for (int off = 32; off > 0; off >>= 1)
        v = fmaxf(v, __shfl_down(v, off, 64));
    __syncthreads();
    if ((tid & 63) == 0) red[tid >> 6] = v;
    __syncthreads();
    return fmaxf(red[0], red[1]);
}
__device__ __forceinline__ float block_sum128(float v, float* red, int tid) {
    #pragma unroll
    for (int off = 32; off > 0; off >>= 1)
        v += __shfl_down(v, off, 64);
    __syncthreads();
    if ((tid & 63) == 0) red[tid >> 6] = v;
    __syncthreads();
    return red[0] + red[1];
}

// ================= fallback pipeline (only if workspace too small) =================
#define FSHIFT 8
__global__ void hist_kernel(const int* __restrict__ dst, int E, int* __restrict__ counts) {
    int stride = gridDim.x * blockDim.x;
    for (int k = blockIdx.x * blockDim.x + threadIdx.x; k < E; k += stride)
        atomicAdd(&counts[dst[k]], 1);
}
__global__ void scan1_kernel(const int* __restrict__ counts, int* __restrict__ offsets,
                             int* __restrict__ blockSums, int N) {
    __shared__ int tile[256];
    int tid = threadIdx.x;
    int i = blockIdx.x * 256 + tid;
    int v = (i < N) ? counts[i] : 0;
    tile[tid] = v;
    __syncthreads();
    for (int off = 1; off < 256; off <<= 1) {
        int t = (tid >= off) ? tile[tid - off] : 0;
        __syncthreads();
        tile[tid] += t;
        __syncthreads();
    }
    int incl = tile[tid];
    if (i < N) offsets[i] = incl - v;
    if (tid == 255) blockSums[blockIdx.x] = incl;
}
__global__ void scan2_kernel(int* __restrict__ bs, int nb) {
    __shared__ int tile[256];
    int tid = threadIdx.x;
    int carry = 0;
    for (int base = 0; base < nb; base += 256) {
        int i = base + tid;
        int v = (i < nb) ? bs[i] : 0;
        __syncthreads();
        tile[tid] = v;
        __syncthreads();
        for (int off = 1; off < 256; off <<= 1) {
            int t = (tid >= off) ? tile[tid - off] : 0;
            __syncthreads();
            tile[tid] += t;
            __syncthreads();
        }
        int incl = tile[tid];
        if (i < nb) bs[i] = incl - v + carry;
        carry += tile[255];
    }
}
__global__ void fill_kernel(const int* __restrict__ src, const int* __restrict__ dst, int E,
                            const int* __restrict__ offsets, const int* __restrict__ bsum,
                            int* __restrict__ cursor, int* __restrict__ perm_src) {
    int stride = gridDim.x * blockDim.x;
    for (int k = blockIdx.x * blockDim.x + threadIdx.x; k < E; k += stride) {
        int j = dst[k];
        int p = offsets[j] + bsum[j >> FSHIFT] + atomicAdd(&cursor[j], 1);
        perm_src[p] = src[k];
    }
}
__global__ void gat_aggregate_f32_kernel(const float* __restrict__ feat_src,
                                         const float* __restrict__ el,
                                         const float* __restrict__ er,
                                         const int* __restrict__ offsets,
                                         const int* __restrict__ bsum,
                                         const int* __restrict__ counts,
                                         const int* __restrict__ perm_src,
                                         float* __restrict__ out, int Nd) {
    __shared__ float w_sh[CHUNK];
    __shared__ int   s_sh[CHUNK];
    __shared__ float red[2];
    int j = blockIdx.x;
    int tid = threadIdx.x;
    int cnt = counts[j];
    size_t orow = (size_t)j * D;
    if (cnt == 0) { out[orow + tid] = 0.0f; return; }
    int beg = offsets[j] + bsum[j >> FSHIFT];
    float erj = er[j];
    float acc = 0.0f;
    float inv;
    if (cnt <= CHUNK) {
        float lmax = -INFINITY;
        for (int t = tid; t < cnt; t += AGG_THREADS) {
            int s = perm_src[beg + t];
            float e = el[s] + erj;
            e = (e >= 0.0f) ? e : 0.01f * e;
            s_sh[t] = s; w_sh[t] = e;
            lmax = fmaxf(lmax, e);
        }
        float m = block_max128(lmax, red, tid);
        float lsum = 0.0f;
        for (int t = tid; t < cnt; t += AGG_THREADS) {
            float a = __expf(w_sh[t] - m);
            w_sh[t] = a; lsum += a;
        }
        float den = block_sum128(lsum, red, tid);
        inv = 1.0f / den;
        __syncthreads();
        for (int t = 0; t < cnt; ++t)
            acc += feat_src[(size_t)s_sh[t] * D + tid] * w_sh[t];
    } else {
        float lmax = -INFINITY;
        for (int t = tid; t < cnt; t += AGG_THREADS) {
            int s = perm_src[beg + t];
            float e = el[s] + erj;
            e = (e >= 0.0f) ? e : 0.01f * e;
            lmax = fmaxf(lmax, e);
        }
        float m = block_max128(lmax, red, tid);
        float lsum = 0.0f;
        for (int t = tid; t < cnt; t += AGG_THREADS) {
            int s = perm_src[beg + t];
            float e = el[s] + erj;
            e = (e >= 0.0f) ? e : 0.01f * e;
            lsum += __expf(e - m);
        }
        float den = block_sum128(lsum, red, tid);
        inv = 1.0f / den;
        for (int bb = 0; bb < cnt; bb += CHUNK) {
            int n = min(CHUNK, cnt - bb);
            __syncthreads();
            for (int t = tid; t < n; t += AGG_THREADS) {
                int s = perm_src[beg + bb + t];
                float e = el[s] + erj;
                e = (e >= 0.0f) ? e : 0.01f * e;
                s_sh[t] = s;
                w_sh[t] = __expf(e - m);
            }
            __syncthreads();
            for (int t = 0; t < n; ++t)
                acc += feat_src[(size_t)s_sh[t] * D + tid] * w_sh[t];
        }
    }
    out[orow + tid] = acc * inv;
}

extern "C" void kernel_launch(void* const* d_in, const int* in_sizes, int n_in,
                              void* d_out, int out_size, void* d_ws, size_t ws_size,
                              hipStream_t stream) {
    const float* feat_src = (const float*)d_in[0];
    const float* feat_dst = (const float*)d_in[1];
    const int*   src      = (const int*)d_in[2];
    const int*   dst      = (const int*)d_in[3];
    const float* attn_l   = (const float*)d_in[4];
    const float* attn_r   = (const float*)d_in[5];
    float* out = (float*)d_out;

    int Ns = in_sizes[0] / D;
    int Nd = in_sizes[1] / D;
    int E  = in_sizes[2];
    int NBK = (Nd + BK - 1) >> BSHIFT;               // fast-path buckets (64 dst)
    int NFB = (Nd + 255) >> FSHIFT;                  // fallback scan blocks (256 dst)
    int NWG = (E + PCHUNK - 1) / PCHUNK;

    char* p = (char*)d_ws;
    auto carve = [&](size_t bytes) { void* r = (void*)p; p += (bytes + 255) & ~(size_t)255; return r; };
    float* el      = (float*)carve((size_t)Ns * 4);
    float* er      = (float*)carve((size_t)Nd * 4);
    int*   counts  = (int*)carve((size_t)Nd * 4);       // fallback only
    int*   offs    = (int*)carve((size_t)Nd * 4);       // fallback only
    int*   gcursor = (int*)carve((size_t)Nd * 4);       // fallback only
    int*   bsums   = (int*)carve((size_t)NFB * 4);      // fallback only
    int2*  tab     = (int2*)carve((size_t)NWG * NBK * 8);
    int*   spill   = (int*)carve((size_t)NBK * PR * 4); // >= E*4, shared w/ fallback perm
    uint2* bins    = (uint2*)carve((size_t)NWG * PCHUNK * 8);
    size_t used    = (size_t)(p - (char*)d_ws);
    size_t bf_bytes = (size_t)Ns * D * 2;
    unsigned short* feat_bf = (unsigned short*)carve(bf_bytes);

    int fast = (NBK <= MAXB && NWG <= MAXWG &&
                used + bf_bytes + 256 <= ws_size) ? 1 : 0;

    int total = Ns + Nd;
    if (fast) {
        prep_kernel<<<(total + 7) / 8, 256, 0, stream>>>(feat_src, feat_dst, attn_l, attn_r,
                                                         el, er, feat_bf, 1, Ns, Nd);
        partition_kernel<<<NWG, 256, 0, stream>>>(src, dst, E, NBK, bins, tab);
        bucket_agg_kernel<<<NBK, 256, 0, stream>>>(bins, tab, NBK, NWG,
                                                   feat_bf, el, er, spill, out, Nd);
    } else {
        hipMemsetAsync(counts, 0, (size_t)Nd * 4, stream);
        hipMemsetAsync(gcursor, 0, (size_t)Nd * 4, stream);
        prep_kernel<<<(total + 7) / 8, 256, 0, stream>>>(feat_src, feat_dst, attn_l, attn_r,
                                                         el, er, nullptr, 0, Ns, Nd);
        hist_kernel<<<2048, 256, 0, stream>>>(dst, E, counts);
        scan1_kernel<<<NFB, 256, 0, stream>>>(counts, offs, bsums, Nd);
        scan2_kernel<<<1, 256, 0, stream>>>(bsums, NFB);
        fill_kernel<<<2048, 256, 0, stream>>>(src, dst, E, offs, bsums, gcursor, spill);
        gat_aggregate_f32_kernel<<<Nd, AGG_THREADS, 0, stream>>>(feat_src, el, er, offs,
                                                                 bsums, counts, spill, out, Nd);
    }
}

// Round 12
// 262.890 us; speedup vs baseline: 1.0525x; 1.0525x over previous
//
#include <hip/hip_runtime.h>
#include <hip/hip_bf16.h>
#include <math.h>

#define D 128
#define AGG_THREADS 128
#define CHUNK 512
#define BSHIFT 8                 // 256 dst nodes per bucket (R2-verified best)
#define MAXB 1024                // max buckets (LDS arrays in partition)
#define MAXWG 1024               // max partition WGs (LDS arrays in bucket kernel)
#define PCHUNK 4096              // edges per partition WG
#define PE 16                    // PCHUNK / 256
#define EBUF_CAP 5120            // LDS staging cap in bucket kernel (mean 4096, 16 sigma)
#define PR 8192                  // perm region stride per bucket (45 sigma)

// ---------- helpers ----------
__device__ __forceinline__ unsigned short f2bf(float f) {
    union { float f; unsigned int u; } c; c.f = f;
    unsigned int u = c.u;
    unsigned int r = (u + 0x7FFFu + ((u >> 16) & 1u)) >> 16;  // RNE
    return (unsigned short)r;
}
__device__ __forceinline__ void unpack2(unsigned int w, float& lo, float& hi) {
    union { unsigned int u; float f; } c;
    c.u = w << 16;          lo = c.f;
    c.u = w & 0xFFFF0000u;  hi = c.f;
}

// ---------- prep: el/er dots + bf16 copy of feat_src; 2 rows per wave, float4 ----------
__global__ void prep_kernel(const float* __restrict__ feat_src,
                            const float* __restrict__ feat_dst,
                            const float* __restrict__ attn_l,
                            const float* __restrict__ attn_r,
                            float* __restrict__ el, float* __restrict__ er,
                            unsigned short* __restrict__ feat_bf, int store_bf,
                            int Ns, int Nd) {
    int half = threadIdx.x >> 5;           // 0..7 (8 rows per 256-thread block)
    int lane = threadIdx.x & 31;
    int node = blockIdx.x * 8 + half;
    if (node >= Ns + Nd) return;
    bool is_src = node < Ns;
    const float* feat = is_src ? feat_src + (size_t)node * D
                               : feat_dst + (size_t)(node - Ns) * D;
    const float* attn = is_src ? attn_l : attn_r;
    float4 a = ((const float4*)attn)[lane];
    float4 v = ((const float4*)feat)[lane];
    if (is_src && store_bf) {
        ushort4 h; h.x = f2bf(v.x); h.y = f2bf(v.y); h.z = f2bf(v.z); h.w = f2bf(v.w);
        ((ushort4*)(feat_bf + (size_t)node * D))[lane] = h;
    }
    float s = v.x * a.x + v.y * a.y + v.z * a.z + v.w * a.w;
    #pragma unroll
    for (int off = 16; off > 0; off >>= 1)
        s += __shfl_xor(s, off, 64);       // xor<=16 stays within each 32-lane half
    if (lane == 0) {
        if (is_src) el[node] = s;
        else        er[node - Ns] = s;
    }
}

// ---------- partition: WG-local counting sort by bucket, ZERO global atomics ----------
__global__ void partition_kernel(const int* __restrict__ src, const int* __restrict__ dst,
                                 int E, int nbk,
                                 uint2* __restrict__ bins,
                                 int* __restrict__ cnt_tab, int* __restrict__ loc_tab) {
    __shared__ int hist[MAXB];
    __shared__ int lstart[MAXB];
    __shared__ int cursor[MAXB];
    __shared__ uint2 sbuf[PCHUNK];         // 32 KB
    int w = blockIdx.x, tid = threadIdx.x;
    int e0 = w * PCHUNK;
    int e1 = min(E, e0 + PCHUNK);
    int n = e1 - e0;

    for (int i = tid; i < nbk; i += 256) hist[i] = 0;
    __syncthreads();

    int es[PE], ed[PE];
    #pragma unroll
    for (int k = 0; k < PE; ++k) {
        int idx = e0 + k * 256 + tid;
        if (idx < e1) {
            es[k] = src[idx];
            ed[k] = dst[idx];
            atomicAdd(&hist[ed[k] >> BSHIFT], 1);
        }
    }
    __syncthreads();

    // exclusive scan of hist[0..nbk) by wave 0, 64-wide chunks
    if (tid < 64) {
        int carry = 0;
        for (int c = 0; c < nbk; c += 64) {
            int i = c + tid;
            int v = (i < nbk) ? hist[i] : 0;
            int x = v;
            #pragma unroll
            for (int off = 1; off < 64; off <<= 1) {
                int t = __shfl_up(x, off, 64);
                if (tid >= off) x += t;
            }
            if (i < nbk) lstart[i] = x - v + carry;
            carry += __shfl(x, 63, 64);
        }
    }
    __syncthreads();

    for (int i = tid; i < nbk; i += 256) {
        cnt_tab[(size_t)w * nbk + i] = hist[i];
        loc_tab[(size_t)w * nbk + i] = lstart[i];
        cursor[i] = 0;
    }
    __syncthreads();

    #pragma unroll
    for (int k = 0; k < PE; ++k) {
        int idx = e0 + k * 256 + tid;
        if (idx < e1) {
            int b = ed[k] >> BSHIFT;
            int r = lstart[b] + atomicAdd(&cursor[b], 1);
            sbuf[r] = make_uint2((unsigned)es[k], (unsigned)ed[k]);
        }
    }
    __syncthreads();

    uint2* obase = bins + (size_t)w * PCHUNK;
    for (int t = tid; t < n; t += 256) obase[t] = sbuf[t];   // coalesced
}

// ---------- bucket kernel: gather segments -> count -> scan -> rank -> perm ----------
// One 256-thread block per bucket. Per-edge parallel gather: binary search the
// segment id in wdst (LDS), one independent global load per edge; count fused.
__global__ void bucket_kernel(const uint2* __restrict__ bins,
                              const int* __restrict__ cnt_tab, const int* __restrict__ loc_tab,
                              int nbk, int nwg,
                              int* __restrict__ counts, int* __restrict__ offs,
                              int* __restrict__ perm, int Nd) {
    __shared__ uint2 ebuf[EBUF_CAP];       // 40 KB
    __shared__ int wcnt[MAXWG];
    __shared__ int wdst[MAXWG];
    __shared__ int sbase[MAXWG];
    __shared__ int cnt256[256];
    __shared__ int off256[256];
    __shared__ int cur256[256];
    __shared__ int tile[256];
    __shared__ int total_sh;

    int b = blockIdx.x, tid = threadIdx.x;
    int base = b << BSHIFT;

    for (int i = tid; i < nwg; i += 256) wcnt[i] = cnt_tab[(size_t)i * nbk + b];
    __syncthreads();
    if (tid < 64) {                        // exclusive scan over nwg segment counts
        int carry = 0;
        for (int c = 0; c < nwg; c += 64) {
            int i = c + tid;
            int v = (i < nwg) ? wcnt[i] : 0;
            int x = v;
            #pragma unroll
            for (int off = 1; off < 64; off <<= 1) {
                int t = __shfl_up(x, off, 64);
                if (tid >= off) x += t;
            }
            if (i < nwg) wdst[i] = x - v + carry;
            carry += __shfl(x, 63, 64);
        }
        if (tid == 0) total_sh = carry;
    }
    cnt256[tid] = 0;
    cur256[tid] = 0;
    __syncthreads();
    int n = total_sh;
    bool fits = (n <= EBUF_CAP);

    if (fits) {
        // per-edge parallel gather: seg id via binary search in wdst
        for (int w = tid; w < nwg; w += 256)
            sbase[w] = w * PCHUNK + loc_tab[(size_t)w * nbk + b] - wdst[w];
        __syncthreads();
        for (int t = tid; t < n; t += 256) {
            int lo = 0, hi = nwg - 1;
            while (lo < hi) {              // last w with wdst[w] <= t
                int mid = (lo + hi + 1) >> 1;
                if (wdst[mid] <= t) lo = mid; else hi = mid - 1;
            }
            uint2 e = bins[(size_t)(sbase[lo] + t)];
            ebuf[t] = e;
            atomicAdd(&cnt256[(int)e.y - base], 1);
        }
    } else {
        // slow path (statistically unreachable): count straight from global
        for (int w = tid; w < nwg; w += 256) {
            int c = wcnt[w];
            const uint2* sp = bins + (size_t)w * PCHUNK + loc_tab[(size_t)w * nbk + b];
            for (int k = 0; k < c; ++k)
                atomicAdd(&cnt256[(int)sp[k].y - base], 1);
        }
        __syncthreads();
    }
    __syncthreads();

    // 256-wide exclusive scan of per-dst counts
    int v = cnt256[tid];
    tile[tid] = v;
    __syncthreads();
    for (int off = 1; off < 256; off <<= 1) {
        int t = (tid >= off) ? tile[tid - off] : 0;
        __syncthreads();
        tile[tid] += t;
        __syncthreads();
    }
    int myoff = tile[tid] - v;
    off256[tid] = myoff;
    int i = base + tid;
    if (i < Nd) {
        int c = v;
        if (myoff + c > PR) c = max(0, PR - myoff);   // paranoia clamp
        counts[i] = c;
        offs[i]   = myoff;
    }
    __syncthreads();

    // rank + write perm into this bucket's fixed region
    size_t rbase = (size_t)b * PR;
    if (fits) {
        for (int t = tid; t < n; t += 256) {
            uint2 e = ebuf[t];
            int d = (int)e.y - base;
            int r = atomicAdd(&cur256[d], 1);
            int slot = off256[d] + r;
            if (slot < PR) perm[rbase + slot] = (int)e.x;
        }
    } else {
        for (int w = tid; w < nwg; w += 256) {
            int c = wcnt[w];
            const uint2* sp = bins + (size_t)w * PCHUNK + loc_tab[(size_t)w * nbk + b];
            for (int k = 0; k < c; ++k) {
                uint2 e = sp[k];
                int d = (int)e.y - base;
                int r = atomicAdd(&cur256[d], 1);
                int slot = off256[d] + r;
                if (slot < PR) perm[rbase + slot] = (int)e.x;
            }
        }
    }
}

// ---------- block reductions (128 threads = 2 waves) for fallback aggregate ----------
__device__ __forceinline__ float block_max128(float v, float* red, int tid) {
    #pragma unroll
    for (int off = 32; off > 0; off >>= 1)
        v = fmaxf(v, __shfl_down(v, off, 64));
    __syncthreads();
    if ((tid & 63) == 0) red[tid >> 6] = v;
    __syncthreads();
    return fmaxf(red[0], red[1]);
}
__device__ __forceinline__ float block_sum128(float v, float* red, int tid) {
    #pragma unroll
    for (int off = 32; off > 0; off >>= 1)
        v += __shfl_down(v, off, 64);
    __syncthreads();
    if ((tid & 63) == 0) red[tid >> 6] = v;
    __syncthreads();
    return red[0] + red[1];
}

// ---------- wave-per-dst bf16 aggregate: no LDS, no barriers, 2-deep pipeline ----------
// 256-thread block = 4 independent waves, one dst node per wave.
// wave64 rule: every __shfl executes with a UNIFORM trip count; source lane is
// clamped to an always-active lane and the accumulate is predicated.
__global__ void gat_aggregate_wave_kernel(const unsigned short* __restrict__ feat_bf,
                                          const float* __restrict__ el,
                                          const float* __restrict__ er,
                                          const int* __restrict__ offs,
                                          const int* __restrict__ counts,
                                          const int* __restrict__ perm,
                                          float* __restrict__ out, int Nd) {
    int wid  = threadIdx.x >> 6;           // wave in block: 0..3
    int lane = threadIdx.x & 63;
    int j = blockIdx.x * 4 + wid;
    if (j >= Nd) return;
    int cnt = counts[j];
    size_t orow = (size_t)j * D;
    if (cnt == 0) {
        ((float2*)(out + orow))[lane] = make_float2(0.0f, 0.0f);  // 64 x 8B = 512B
        return;
    }
    size_t beg = (size_t)(j >> BSHIFT) * PR + (size_t)offs[j];
    float erj = er[j];
    int sg = lane >> 4, u = lane & 15;
    const unsigned short* fb = feat_bf + (size_t)u * 8;
    float acc[8];
    #pragma unroll
    for (int k = 0; k < 8; ++k) acc[k] = 0.0f;

    if (cnt <= 64) {
        // one edge per lane, everything in registers
        int s = 0; float e = -INFINITY;
        if (lane < cnt) {
            s = perm[beg + lane];
            float t = el[s] + erj;
            e = (t >= 0.0f) ? t : 0.01f * t;   // leaky_relu
        }
        float m = e;
        #pragma unroll
        for (int off = 32; off > 0; off >>= 1)
            m = fmaxf(m, __shfl_xor(m, off, 64));
        float a = (lane < cnt) ? __expf(e - m) : 0.0f;
        float den = a;
        #pragma unroll
        for (int off = 32; off > 0; off >>= 1)
            den += __shfl_xor(den, off, 64);
        a *= (1.0f / den);                      // pre-normalized weight
        int nit = (cnt + 3) >> 2;               // uniform trip count for all lanes
        int it = 0;
        for (; it + 2 <= nit; it += 2) {        // 2-deep: two rows in flight
            int t0 = sg + (it << 2);            // t0 < cnt guaranteed in this loop
            int t1 = t0 + 4;
            int u1 = (t1 < cnt) ? t1 : 0;
            float w0 = __shfl(a, t0, 64);
            int   s0 = __shfl(s, t0, 64);
            float w1 = __shfl(a, u1, 64);
            int   s1 = __shfl(s, u1, 64);
            bool p1 = (t1 < cnt);
            uint4 v0 = *(const uint4*)(fb + (size_t)s0 * D);
            uint4 v1 = p1 ? *(const uint4*)(fb + (size_t)s1 * D) : make_uint4(0,0,0,0);
            float f[8];
            unpack2(v0.x, f[0], f[1]); unpack2(v0.y, f[2], f[3]);
            unpack2(v0.z, f[4], f[5]); unpack2(v0.w, f[6], f[7]);
            #pragma unroll
            for (int k = 0; k < 8; ++k) acc[k] += w0 * f[k];
            if (p1) {
                unpack2(v1.x, f[0], f[1]); unpack2(v1.y, f[2], f[3]);
                unpack2(v1.z, f[4], f[5]); unpack2(v1.w, f[6], f[7]);
                #pragma unroll
                for (int k = 0; k < 8; ++k) acc[k] += w1 * f[k];
            }
        }
        if (it < nit) {                         // tail
            int t0 = sg + (it << 2);
            int u0 = (t0 < cnt) ? t0 : 0;
            float w0 = __shfl(a, u0, 64);
            int   s0 = __shfl(s, u0, 64);
            if (t0 < cnt) {
                uint4 v0 = *(const uint4*)(fb + (size_t)s0 * D);
                float f[8];
                unpack2(v0.x, f[0], f[1]); unpack2(v0.y, f[2], f[3]);
                unpack2(v0.z, f[4], f[5]); unpack2(v0.w, f[6], f[7]);
                #pragma unroll
                for (int k = 0; k < 8; ++k) acc[k] += w0 * f[k];
            }
        }
    } else {
        // chunked recompute path (cnt > 64)
        float lmax = -INFINITY;
        for (int t = lane; t < cnt; t += 64) {
            int s = perm[beg + t];
            float e = el[s] + erj;
            e = (e >= 0.0f) ? e : 0.01f * e;
            lmax = fmaxf(lmax, e);
        }
        float m = lmax;
        #pragma unroll
        for (int off = 32; off > 0; off >>= 1)
            m = fmaxf(m, __shfl_xor(m, off, 64));
        float lsum = 0.0f;
        for (int t = lane; t < cnt; t += 64) {
            int s = perm[beg + t];
            float e = el[s] + erj;
            e = (e >= 0.0f) ? e : 0.01f * e;
            lsum += __expf(e - m);
        }
        #pragma unroll
        for (int off = 32; off > 0; off >>= 1)
            lsum += __shfl_xor(lsum, off, 64);
        float inv = 1.0f / lsum;
        for (int bb = 0; bb < cnt; bb += 64) {
            int nn = min(64, cnt - bb);
            int s = 0; float a = 0.0f;
            if (lane < nn) {
                s = perm[beg + bb + lane];
                float e = el[s] + erj;
                e = (e >= 0.0f) ? e : 0.01f * e;
                a = __expf(e - m) * inv;
            }
            int nit = (nn + 3) >> 2;            // uniform trip count
            for (int it = 0; it < nit; ++it) {
                int t = sg + (it << 2);
                int tt = (t < nn) ? t : 0;
                float w = __shfl(a, tt, 64);
                int st  = __shfl(s, tt, 64);
                if (t < nn) {
                    uint4 v = *(const uint4*)(fb + (size_t)st * D);
                    float f[8];
                    unpack2(v.x, f[0], f[1]); unpack2(v.y, f[2], f[3]);
                    unpack2(v.z, f[4], f[5]); unpack2(v.w, f[6], f[7]);
                    #pragma unroll
                    for (int k = 0; k < 8; ++k) acc[k] += w * f[k];
                }
            }
        }
    }
    // reduce across the 4 subgroups (lane bits 4,5) — all 64 lanes active here
    #pragma unroll
    for (int k = 0; k < 8; ++k) {
        acc[k] += __shfl_xor(acc[k], 16, 64);
        acc[k] += __shfl_xor(acc[k], 32, 64);
    }
    if (sg == 0) {
        float* op = out + orow + (size_t)u * 8;
        ((float4*)op)[0] = make_float4(acc[0], acc[1], acc[2], acc[3]);
        ((float4*)op)[1] = make_float4(acc[4], acc[5], acc[6], acc[7]);
    }
}

// ================= fallback pipeline (only if workspace too small) =================
__global__ void hist_kernel(const int* __restrict__ dst, int E, int* __restrict__ counts) {
    int stride = gridDim.x * blockDim.x;
    for (int k = blockIdx.x * blockDim.x + threadIdx.x; k < E; k += stride)
        atomicAdd(&counts[dst[k]], 1);
}
__global__ void scan1_kernel(const int* __restrict__ counts, int* __restrict__ offsets,
                             int* __restrict__ blockSums, int N) {
    __shared__ int tile[256];
    int tid = threadIdx.x;
    int i = blockIdx.x * 256 + tid;
    int v = (i < N) ? counts[i] : 0;
    tile[tid] = v;
    __syncthreads();
    for (int off = 1; off < 256; off <<= 1) {
        int t = (tid >= off) ? tile[tid - off] : 0;
        __syncthreads();
        tile[tid] += t;
        __syncthreads();
    }
    int incl = tile[tid];
    if (i < N) offsets[i] = incl - v;
    if (tid == 255) blockSums[blockIdx.x] = incl;
}
__global__ void scan2_kernel(int* __restrict__ bs, int nb) {
    __shared__ int tile[256];
    int tid = threadIdx.x;
    int carry = 0;
    for (int base = 0; base < nb; base += 256) {
        int i = base + tid;
        int v = (i < nb) ? bs[i] : 0;
        __syncthreads();
        tile[tid] = v;
        __syncthreads();
        for (int off = 1; off < 256; off <<= 1) {
            int t = (tid >= off) ? tile[tid - off] : 0;
            __syncthreads();
            tile[tid] += t;
            __syncthreads();
        }
        int incl = tile[tid];
        if (i < nb) bs[i] = incl - v + carry;
        carry += tile[255];
    }
}
__global__ void fill_kernel(const int* __restrict__ src, const int* __restrict__ dst, int E,
                            const int* __restrict__ offsets, const int* __restrict__ bsum,
                            int* __restrict__ cursor, int* __restrict__ perm_src) {
    int stride = gridDim.x * blockDim.x;
    for (int k = blockIdx.x * blockDim.x + threadIdx.x; k < E; k += stride) {
        int j = dst[k];
        int p = offsets[j] + bsum[j >> BSHIFT] + atomicAdd(&cursor[j], 1);
        perm_src[p] = src[k];
    }
}
__global__ void gat_aggregate_f32_kernel(const float* __restrict__ feat_src,
                                         const float* __restrict__ el,
                                         const float* __restrict__ er,
                                         const int* __restrict__ offsets,
                                         const int* __restrict__ bsum,
                                         const int* __restrict__ counts,
                                         const int* __restrict__ perm_src,
                                         float* __restrict__ out, int Nd) {
    __shared__ float w_sh[CHUNK];
    __shared__ int   s_sh[CHUNK];
    __shared__ float red[2];
    int j = blockIdx.x;
    int tid = threadIdx.x;
    int cnt = counts[j];
    size_t orow = (size_t)j * D;
    if (cnt == 0) { out[orow + tid] = 0.0f; return; }
    int beg = offsets[j] + bsum[j >> BSHIFT];
    float erj = er[j];
    float acc = 0.0f;
    float inv;
    if (cnt <= CHUNK) {
        float lmax = -INFINITY;
        for (int t = tid; t < cnt; t += AGG_THREADS) {
            int s = perm_src[beg + t];
            float e = el[s] + erj;
            e = (e >= 0.0f) ? e : 0.01f * e;
            s_sh[t] = s; w_sh[t] = e;
            lmax = fmaxf(lmax, e);
        }
        float m = block_max128(lmax, red, tid);
        float lsum = 0.0f;
        for (int t = tid; t < cnt; t += AGG_THREADS) {
            float a = __expf(w_sh[t] - m);
            w_sh[t] = a; lsum += a;
        }
        float den = block_sum128(lsum, red, tid);
        inv = 1.0f / den;
        __syncthreads();
        for (int t = 0; t < cnt; ++t)
            acc += feat_src[(size_t)s_sh[t] * D + tid] * w_sh[t];
    } else {
        float lmax = -INFINITY;
        for (int t = tid; t < cnt; t += AGG_THREADS) {
            int s = perm_src[beg + t];
            float e = el[s] + erj;
            e = (e >= 0.0f) ? e : 0.01f * e;
            lmax = fmaxf(lmax, e);
        }
        float m = block_max128(lmax, red, tid);
        float lsum = 0.0f;
        for (int t = tid; t < cnt; t += AGG_THREADS) {
            int s = perm_src[beg + t];
            float e = el[s] + erj;
            e = (e >= 0.0f) ? e : 0.01f * e;
            lsum += __expf(e - m);
        }
        float den = block_sum128(lsum, red, tid);
        inv = 1.0f / den;
        for (int bb = 0; bb < cnt; bb += CHUNK) {
            int n = min(CHUNK, cnt - bb);
            __syncthreads();
            for (int t = tid; t < n; t += AGG_THREADS) {
                int s = perm_src[beg + bb + t];
                float e = el[s] + erj;
                e = (e >= 0.0f) ? e : 0.01f * e;
                s_sh[t] = s;
                w_sh[t] = __expf(e - m);
            }
            __syncthreads();
            for (int t = 0; t < n; ++t)
                acc += feat_src[(size_t)s_sh[t] * D + tid] * w_sh[t];
        }
    }
    out[orow + tid] = acc * inv;
}

extern "C" void kernel_launch(void* const* d_in, const int* in_sizes, int n_in,
                              void* d_out, int out_size, void* d_ws, size_t ws_size,
                              hipStream_t stream) {
    const float* feat_src = (const float*)d_in[0];
    const float* feat_dst = (const float*)d_in[1];
    const int*   src      = (const int*)d_in[2];
    const int*   dst      = (const int*)d_in[3];
    const float* attn_l   = (const float*)d_in[4];
    const float* attn_r   = (const float*)d_in[5];
    float* out = (float*)d_out;

    int Ns = in_sizes[0] / D;
    int Nd = in_sizes[1] / D;
    int E  = in_sizes[2];
    int NBK = (Nd + (1 << BSHIFT) - 1) >> BSHIFT;
    int NWG = (E + PCHUNK - 1) / PCHUNK;

    char* p = (char*)d_ws;
    auto carve = [&](size_t bytes) { void* r = (void*)p; p += (bytes + 255) & ~(size_t)255; return r; };
    float* el      = (float*)carve((size_t)Ns * 4);
    float* er      = (float*)carve((size_t)Nd * 4);
    int*   counts  = (int*)carve((size_t)Nd * 4);
    int*   offs    = (int*)carve((size_t)Nd * 4);       // fallback: 'offsets'
    int*   gcursor = (int*)carve((size_t)Nd * 4);       // fallback only
    int*   bsums   = (int*)carve((size_t)NBK * 4);      // fallback only
    int*   cnt_tab = (int*)carve((size_t)NWG * NBK * 4);
    int*   loc_tab = (int*)carve((size_t)NWG * NBK * 4);
    int*   perm    = (int*)carve((size_t)NBK * PR * 4); // >= E*4, shared w/ fallback
    uint2* bins    = (uint2*)carve((size_t)NWG * PCHUNK * 8);
    size_t used    = (size_t)(p - (char*)d_ws);
    size_t bf_bytes = (size_t)Ns * D * 2;
    unsigned short* feat_bf = (unsigned short*)carve(bf_bytes);

    int fast = (NBK <= MAXB && NWG <= MAXWG &&
                used + bf_bytes + 256 <= ws_size) ? 1 : 0;

    int total = Ns + Nd;
    if (fast) {
        prep_kernel<<<(total + 7) / 8, 256, 0, stream>>>(feat_src, feat_dst, attn_l, attn_r,
                                                         el, er, feat_bf, 1, Ns, Nd);
        partition_kernel<<<NWG, 256, 0, stream>>>(src, dst, E, NBK, bins, cnt_tab, loc_tab);
        bucket_kernel<<<NBK, 256, 0, stream>>>(bins, cnt_tab, loc_tab, NBK, NWG,
                                               counts, offs, perm, Nd);
        gat_aggregate_wave_kernel<<<(Nd + 3) / 4, 256, 0, stream>>>(feat_bf, el, er, offs,
                                                                    counts, perm, out, Nd);
    } else {
        hipMemsetAsync(counts, 0, (size_t)Nd * 4, stream);
        hipMemsetAsync(gcursor, 0, (size_t)Nd * 4, stream);
        prep_kernel<<<(total + 7) / 8, 256, 0, stream>>>(feat_src, feat_dst, attn_l, attn_r,
                                                         el, er, nullptr, 0, Ns, Nd);
        hist_kernel<<<2048, 256, 0, stream>>>(dst, E, counts);
        scan1_kernel<<<NBK, 256, 0, stream>>>(counts, offs, bsums, Nd);
        scan2_kernel<<<1, 256, 0, stream>>>(bsums, NBK);
        fill_kernel<<<2048, 256, 0, stream>>>(src, dst, E, offs, bsums, gcursor, perm);
        gat_aggregate_f32_kernel<<<Nd, AGG_THREADS, 0, stream>>>(feat_src, el, er, offs,
                                                                 bsums, counts, perm, out, Nd);
    }
}

// Round 13
// 253.955 us; speedup vs baseline: 1.0896x; 1.0352x over previous
//
#include <hip/hip_runtime.h>
#include <hip/hip_bf16.h>
#include <math.h>

#define D 128
#define AGG_THREADS 128
#define CHUNK 512
#define BSHIFT 8                 // 256 dst nodes per bucket (R2/R12-verified best)
#define MAXB 512                 // max buckets (nbk=391 at Nd=100K)
#define MAXWG 1024               // max partition WGs (LDS arrays in bucket kernel)
#define PCHUNK 2048              // edges per partition WG (halved: 2x grid, 22 KB LDS)
#define PE 8                     // PCHUNK / 256
#define EBUF_CAP 5120            // LDS staging cap in bucket kernel (mean 4096, 16 sigma)
#define PR 8192                  // perm region stride per bucket (45 sigma)

// ---------- helpers ----------
__device__ __forceinline__ unsigned short f2bf(float f) {
    union { float f; unsigned int u; } c; c.f = f;
    unsigned int u = c.u;
    unsigned int r = (u + 0x7FFFu + ((u >> 16) & 1u)) >> 16;  // RNE
    return (unsigned short)r;
}
__device__ __forceinline__ void unpack2(unsigned int w, float& lo, float& hi) {
    union { unsigned int u; float f; } c;
    c.u = w << 16;          lo = c.f;
    c.u = w & 0xFFFF0000u;  hi = c.f;
}

// ---------- FUSED prep + partition: heterogeneous block roles ----------
// Blocks [0, nwg): partition role -- WG-local counting sort of a 2048-edge
//   chunk by 256-dst bucket, zero global atomics (R12-verified structure).
// Blocks [nwg, nwg+prep_blocks): prep role -- el/er dots + bf16 feat copy.
// The two roles touch disjoint data; fusing them lets partition's
// latency-bound phases hide under prep's HBM streaming.
__global__ void prep_partition_kernel(const float* __restrict__ feat_src,
                                      const float* __restrict__ feat_dst,
                                      const float* __restrict__ attn_l,
                                      const float* __restrict__ attn_r,
                                      float* __restrict__ el, float* __restrict__ er,
                                      unsigned short* __restrict__ feat_bf,
                                      int Ns, int Nd,
                                      const int* __restrict__ src,
                                      const int* __restrict__ dst,
                                      int E, int nbk, int nwg,
                                      uint2* __restrict__ bins,
                                      int* __restrict__ cnt_tab,
                                      int* __restrict__ loc_tab) {
    __shared__ int hist[MAXB];
    __shared__ int lstart[MAXB];
    __shared__ int cursor[MAXB];
    __shared__ uint2 sbuf[PCHUNK];         // 16 KB; total LDS ~22 KB
    int tid = threadIdx.x;

    if ((int)blockIdx.x < nwg) {
        // ---------------- partition role ----------------
        int w = blockIdx.x;
        int e0 = w * PCHUNK;
        int e1 = min(E, e0 + PCHUNK);
        int n = e1 - e0;

        for (int i = tid; i < nbk; i += 256) hist[i] = 0;
        __syncthreads();

        int es[PE], ed[PE];
        #pragma unroll
        for (int k = 0; k < PE; ++k) {
            int idx = e0 + k * 256 + tid;
            if (idx < e1) {
                es[k] = src[idx];
                ed[k] = dst[idx];
                atomicAdd(&hist[ed[k] >> BSHIFT], 1);
            }
        }
        __syncthreads();

        // exclusive scan of hist[0..nbk) by wave 0, 64-wide chunks (nbk<=512: <=8)
        if (tid < 64) {
            int carry = 0;
            for (int c = 0; c < nbk; c += 64) {
                int i = c + tid;
                int v = (i < nbk) ? hist[i] : 0;
                int x = v;
                #pragma unroll
                for (int off = 1; off < 64; off <<= 1) {
                    int t = __shfl_up(x, off, 64);
                    if (tid >= off) x += t;
                }
                if (i < nbk) lstart[i] = x - v + carry;
                carry += __shfl(x, 63, 64);
            }
        }
        __syncthreads();

        for (int i = tid; i < nbk; i += 256) {
            cnt_tab[(size_t)w * nbk + i] = hist[i];
            loc_tab[(size_t)w * nbk + i] = lstart[i];
            cursor[i] = 0;
        }
        __syncthreads();

        #pragma unroll
        for (int k = 0; k < PE; ++k) {
            int idx = e0 + k * 256 + tid;
            if (idx < e1) {
                int b = ed[k] >> BSHIFT;
                int r = lstart[b] + atomicAdd(&cursor[b], 1);
                sbuf[r] = make_uint2((unsigned)es[k], (unsigned)ed[k]);
            }
        }
        __syncthreads();

        uint2* obase = bins + (size_t)w * PCHUNK;
        for (int t = tid; t < n; t += 256) obase[t] = sbuf[t];   // coalesced
    } else {
        // ---------------- prep role ----------------
        int half = tid >> 5;               // 0..7 (8 rows per 256-thread block)
        int lane = tid & 31;
        int node = ((int)blockIdx.x - nwg) * 8 + half;
        if (node >= Ns + Nd) return;
        bool is_src = node < Ns;
        const float* feat = is_src ? feat_src + (size_t)node * D
                                   : feat_dst + (size_t)(node - Ns) * D;
        const float* attn = is_src ? attn_l : attn_r;
        float4 a = ((const float4*)attn)[lane];
        float4 v = ((const float4*)feat)[lane];
        if (is_src) {
            ushort4 h; h.x = f2bf(v.x); h.y = f2bf(v.y); h.z = f2bf(v.z); h.w = f2bf(v.w);
            ((ushort4*)(feat_bf + (size_t)node * D))[lane] = h;
        }
        float s = v.x * a.x + v.y * a.y + v.z * a.z + v.w * a.w;
        #pragma unroll
        for (int off = 16; off > 0; off >>= 1)
            s += __shfl_xor(s, off, 64);   // xor<=16 stays within each 32-lane half
        if (lane == 0) {
            if (is_src) el[node] = s;
            else        er[node - Ns] = s;
        }
    }
}

// ---------- standalone prep (fallback path only) ----------
__global__ void prep_kernel(const float* __restrict__ feat_src,
                            const float* __restrict__ feat_dst,
                            const float* __restrict__ attn_l,
                            const float* __restrict__ attn_r,
                            float* __restrict__ el, float* __restrict__ er,
                            unsigned short* __restrict__ feat_bf, int store_bf,
                            int Ns, int Nd) {
    int half = threadIdx.x >> 5;
    int lane = threadIdx.x & 31;
    int node = blockIdx.x * 8 + half;
    if (node >= Ns + Nd) return;
    bool is_src = node < Ns;
    const float* feat = is_src ? feat_src + (size_t)node * D
                               : feat_dst + (size_t)(node - Ns) * D;
    const float* attn = is_src ? attn_l : attn_r;
    float4 a = ((const float4*)attn)[lane];
    float4 v = ((const float4*)feat)[lane];
    if (is_src && store_bf) {
        ushort4 h; h.x = f2bf(v.x); h.y = f2bf(v.y); h.z = f2bf(v.z); h.w = f2bf(v.w);
        ((ushort4*)(feat_bf + (size_t)node * D))[lane] = h;
    }
    float s = v.x * a.x + v.y * a.y + v.z * a.z + v.w * a.w;
    #pragma unroll
    for (int off = 16; off > 0; off >>= 1)
        s += __shfl_xor(s, off, 64);
    if (lane == 0) {
        if (is_src) el[node] = s;
        else        er[node - Ns] = s;
    }
}

// ---------- bucket kernel: gather segments -> count -> scan -> rank -> perm ----------
// One 256-thread block per bucket. Per-edge parallel gather: binary search the
// segment id in wdst (LDS), one independent global load per edge; count fused.
__global__ void bucket_kernel(const uint2* __restrict__ bins,
                              const int* __restrict__ cnt_tab, const int* __restrict__ loc_tab,
                              int nbk, int nwg,
                              int* __restrict__ counts, int* __restrict__ offs,
                              int* __restrict__ perm, int Nd) {
    __shared__ uint2 ebuf[EBUF_CAP];       // 40 KB
    __shared__ int wcnt[MAXWG];
    __shared__ int wdst[MAXWG];
    __shared__ int sbase[MAXWG];
    __shared__ int cnt256[256];
    __shared__ int off256[256];
    __shared__ int cur256[256];
    __shared__ int tile[256];
    __shared__ int total_sh;

    int b = blockIdx.x, tid = threadIdx.x;
    int base = b << BSHIFT;

    for (int i = tid; i < nwg; i += 256) wcnt[i] = cnt_tab[(size_t)i * nbk + b];
    __syncthreads();
    if (tid < 64) {                        // exclusive scan over nwg segment counts
        int carry = 0;
        for (int c = 0; c < nwg; c += 64) {
            int i = c + tid;
            int v = (i < nwg) ? wcnt[i] : 0;
            int x = v;
            #pragma unroll
            for (int off = 1; off < 64; off <<= 1) {
                int t = __shfl_up(x, off, 64);
                if (tid >= off) x += t;
            }
            if (i < nwg) wdst[i] = x - v + carry;
            carry += __shfl(x, 63, 64);
        }
        if (tid == 0) total_sh = carry;
    }
    cnt256[tid] = 0;
    cur256[tid] = 0;
    __syncthreads();
    int n = total_sh;
    bool fits = (n <= EBUF_CAP);

    if (fits) {
        // per-edge parallel gather: seg id via binary search in wdst
        for (int w = tid; w < nwg; w += 256)
            sbase[w] = w * PCHUNK + loc_tab[(size_t)w * nbk + b] - wdst[w];
        __syncthreads();
        for (int t = tid; t < n; t += 256) {
            int lo = 0, hi = nwg - 1;
            while (lo < hi) {              // last w with wdst[w] <= t
                int mid = (lo + hi + 1) >> 1;
                if (wdst[mid] <= t) lo = mid; else hi = mid - 1;
            }
            uint2 e = bins[(size_t)(sbase[lo] + t)];
            ebuf[t] = e;
            atomicAdd(&cnt256[(int)e.y - base], 1);
        }
    } else {
        // slow path (statistically unreachable): count straight from global
        for (int w = tid; w < nwg; w += 256) {
            int c = wcnt[w];
            const uint2* sp = bins + (size_t)w * PCHUNK + loc_tab[(size_t)w * nbk + b];
            for (int k = 0; k < c; ++k)
                atomicAdd(&cnt256[(int)sp[k].y - base], 1);
        }
        __syncthreads();
    }
    __syncthreads();

    // 256-wide exclusive scan of per-dst counts
    int v = cnt256[tid];
    tile[tid] = v;
    __syncthreads();
    for (int off = 1; off < 256; off <<= 1) {
        int t = (tid >= off) ? tile[tid - off] : 0;
        __syncthreads();
        tile[tid] += t;
        __syncthreads();
    }
    int myoff = tile[tid] - v;
    off256[tid] = myoff;
    int i = base + tid;
    if (i < Nd) {
        int c = v;
        if (myoff + c > PR) c = max(0, PR - myoff);   // paranoia clamp
        counts[i] = c;
        offs[i]   = myoff;
    }
    __syncthreads();

    // rank + write perm into this bucket's fixed region
    size_t rbase = (size_t)b * PR;
    if (fits) {
        for (int t = tid; t < n; t += 256) {
            uint2 e = ebuf[t];
            int d = (int)e.y - base;
            int r = atomicAdd(&cur256[d], 1);
            int slot = off256[d] + r;
            if (slot < PR) perm[rbase + slot] = (int)e.x;
        }
    } else {
        for (int w = tid; w < nwg; w += 256) {
            int c = wcnt[w];
            const uint2* sp = bins + (size_t)w * PCHUNK + loc_tab[(size_t)w * nbk + b];
            for (int k = 0; k < c; ++k) {
                uint2 e = sp[k];
                int d = (int)e.y - base;
                int r = atomicAdd(&cur256[d], 1);
                int slot = off256[d] + r;
                if (slot < PR) perm[rbase + slot] = (int)e.x;
            }
        }
    }
}

// ---------- block reductions (128 threads = 2 waves) for fallback aggregate ----------
__device__ __forceinline__ float block_max128(float v, float* red, int tid) {
    #pragma unroll
    for (int off = 32; off > 0; off >>= 1)
        v = fmaxf(v, __shfl_down(v, off, 64));
    __syncthreads();
    if ((tid & 63) == 0) red[tid >> 6] = v;
    __syncthreads();
    return fmaxf(red[0], red[1]);
}
__device__ __forceinline__ float block_sum128(float v, float* red, int tid) {
    #pragma unroll
    for (int off = 32; off > 0; off >>= 1)
        v += __shfl_down(v, off, 64);
    __syncthreads();
    if ((tid & 63) == 0) red[tid >> 6] = v;
    __syncthreads();
    return red[0] + red[1];
}

// ---------- wave-per-dst bf16 aggregate: no LDS, no barriers, 2-deep pipeline ----------
__global__ void gat_aggregate_wave_kernel(const unsigned short* __restrict__ feat_bf,
                                          const float* __restrict__ el,
                                          const float* __restrict__ er,
                                          const int* __restrict__ offs,
                                          const int* __restrict__ counts,
                                          const int* __restrict__ perm,
                                          float* __restrict__ out, int Nd) {
    int wid  = threadIdx.x >> 6;           // wave in block: 0..3
    int lane = threadIdx.x & 63;
    int j = blockIdx.x * 4 + wid;
    if (j >= Nd) return;
    int cnt = counts[j];
    size_t orow = (size_t)j * D;
    if (cnt == 0) {
        ((float2*)(out + orow))[lane] = make_float2(0.0f, 0.0f);  // 64 x 8B = 512B
        return;
    }
    size_t beg = (size_t)(j >> BSHIFT) * PR + (size_t)offs[j];
    float erj = er[j];
    int sg = lane >> 4, u = lane & 15;
    const unsigned short* fb = feat_bf + (size_t)u * 8;
    float acc[8];
    #pragma unroll
    for (int k = 0; k < 8; ++k) acc[k] = 0.0f;

    if (cnt <= 64) {
        // one edge per lane, everything in registers
        int s = 0; float e = -INFINITY;
        if (lane < cnt) {
            s = perm[beg + lane];
            float t = el[s] + erj;
            e = (t >= 0.0f) ? t : 0.01f * t;   // leaky_relu
        }
        float m = e;
        #pragma unroll
        for (int off = 32; off > 0; off >>= 1)
            m = fmaxf(m, __shfl_xor(m, off, 64));
        float a = (lane < cnt) ? __expf(e - m) : 0.0f;
        float den = a;
        #pragma unroll
        for (int off = 32; off > 0; off >>= 1)
            den += __shfl_xor(den, off, 64);
        a *= (1.0f / den);                      // pre-normalized weight
        int nit = (cnt + 3) >> 2;               // uniform trip count for all lanes
        int it = 0;
        for (; it + 2 <= nit; it += 2) {        // 2-deep: two rows in flight
            int t0 = sg + (it << 2);            // t0 < cnt guaranteed in this loop
            int t1 = t0 + 4;
            int u1 = (t1 < cnt) ? t1 : 0;
            float w0 = __shfl(a, t0, 64);
            int   s0 = __shfl(s, t0, 64);
            float w1 = __shfl(a, u1, 64);
            int   s1 = __shfl(s, u1, 64);
            bool p1 = (t1 < cnt);
            uint4 v0 = *(const uint4*)(fb + (size_t)s0 * D);
            uint4 v1 = p1 ? *(const uint4*)(fb + (size_t)s1 * D) : make_uint4(0,0,0,0);
            float f[8];
            unpack2(v0.x, f[0], f[1]); unpack2(v0.y, f[2], f[3]);
            unpack2(v0.z, f[4], f[5]); unpack2(v0.w, f[6], f[7]);
            #pragma unroll
            for (int k = 0; k < 8; ++k) acc[k] += w0 * f[k];
            if (p1) {
                unpack2(v1.x, f[0], f[1]); unpack2(v1.y, f[2], f[3]);
                unpack2(v1.z, f[4], f[5]); unpack2(v1.w, f[6], f[7]);
                #pragma unroll
                for (int k = 0; k < 8; ++k) acc[k] += w1 * f[k];
            }
        }
        if (it < nit) {                         // tail
            int t0 = sg + (it << 2);
            int u0 = (t0 < cnt) ? t0 : 0;
            float w0 = __shfl(a, u0, 64);
            int   s0 = __shfl(s, u0, 64);
            if (t0 < cnt) {
                uint4 v0 = *(const uint4*)(fb + (size_t)s0 * D);
                float f[8];
                unpack2(v0.x, f[0], f[1]); unpack2(v0.y, f[2], f[3]);
                unpack2(v0.z, f[4], f[5]); unpack2(v0.w, f[6], f[7]);
                #pragma unroll
                for (int k = 0; k < 8; ++k) acc[k] += w0 * f[k];
            }
        }
    } else {
        // chunked recompute path (cnt > 64)
        float lmax = -INFINITY;
        for (int t = lane; t < cnt; t += 64) {
            int s = perm[beg + t];
            float e = el[s] + erj;
            e = (e >= 0.0f) ? e : 0.01f * e;
            lmax = fmaxf(lmax, e);
        }
        float m = lmax;
        #pragma unroll
        for (int off = 32; off > 0; off >>= 1)
            m = fmaxf(m, __shfl_xor(m, off, 64));
        float lsum = 0.0f;
        for (int t = lane; t < cnt; t += 64) {
            int s = perm[beg + t];
            float e = el[s] + erj;
            e = (e >= 0.0f) ? e : 0.01f * e;
            lsum += __expf(e - m);
        }
        #pragma unroll
        for (int off = 32; off > 0; off >>= 1)
            lsum += __shfl_xor(lsum, off, 64);
        float inv = 1.0f / lsum;
        for (int bb = 0; bb < cnt; bb += 64) {
            int nn = min(64, cnt - bb);
            int s = 0; float a = 0.0f;
            if (lane < nn) {
                s = perm[beg + bb + lane];
                float e = el[s] + erj;
                e = (e >= 0.0f) ? e : 0.01f * e;
                a = __expf(e - m) * inv;
            }
            int nit = (nn + 3) >> 2;            // uniform trip count
            for (int it = 0; it < nit; ++it) {
                int t = sg + (it << 2);
                int tt = (t < nn) ? t : 0;
                float w = __shfl(a, tt, 64);
                int st  = __shfl(s, tt, 64);
                if (t < nn) {
                    uint4 v = *(const uint4*)(fb + (size_t)st * D);
                    float f[8];
                    unpack2(v.x, f[0], f[1]); unpack2(v.y, f[2], f[3]);
                    unpack2(v.z, f[4], f[5]); unpack2(v.w, f[6], f[7]);
                    #pragma unroll
                    for (int k = 0; k < 8; ++k) acc[k] += w * f[k];
                }
            }
        }
    }
    // reduce across the 4 subgroups (lane bits 4,5) — all 64 lanes active here
    #pragma unroll
    for (int k = 0; k < 8; ++k) {
        acc[k] += __shfl_xor(acc[k], 16, 64);
        acc[k] += __shfl_xor(acc[k], 32, 64);
    }
    if (sg == 0) {
        float* op = out + orow + (size_t)u * 8;
        ((float4*)op)[0] = make_float4(acc[0], acc[1], acc[2], acc[3]);
        ((float4*)op)[1] = make_float4(acc[4], acc[5], acc[6], acc[7]);
    }
}

// ================= fallback pipeline (only if workspace too small) =================
__global__ void hist_kernel(const int* __restrict__ dst, int E, int* __restrict__ counts) {
    int stride = gridDim.x * blockDim.x;
    for (int k = blockIdx.x * blockDim.x + threadIdx.x; k < E; k += stride)
        atomicAdd(&counts[dst[k]], 1);
}
__global__ void scan1_kernel(const int* __restrict__ counts, int* __restrict__ offsets,
                             int* __restrict__ blockSums, int N) {
    __shared__ int tile[256];
    int tid = threadIdx.x;
    int i = blockIdx.x * 256 + tid;
    int v = (i < N) ? counts[i] : 0;
    tile[tid] = v;
    __syncthreads();
    for (int off = 1; off < 256; off <<= 1) {
        int t = (tid >= off) ? tile[tid - off] : 0;
        __syncthreads();
        tile[tid] += t;
        __syncthreads();
    }
    int incl = tile[tid];
    if (i < N) offsets[i] = incl - v;
    if (tid == 255) blockSums[blockIdx.x] = incl;
}
__global__ void scan2_kernel(int* __restrict__ bs, int nb) {
    __shared__ int tile[256];
    int tid = threadIdx.x;
    int carry = 0;
    for (int base = 0; base < nb; base += 256) {
        int i = base + tid;
        int v = (i < nb) ? bs[i] : 0;
        __syncthreads();
        tile[tid] = v;
        __syncthreads();
        for (int off = 1; off < 256; off <<= 1) {
            int t = (tid >= off) ? tile[tid - off] : 0;
            __syncthreads();
            tile[tid] += t;
            __syncthreads();
        }
        int incl = tile[tid];
        if (i < nb) bs[i] = incl - v + carry;
        carry += tile[255];
    }
}
__global__ void fill_kernel(const int* __restrict__ src, const int* __restrict__ dst, int E,
                            const int* __restrict__ offsets, const int* __restrict__ bsum,
                            int* __restrict__ cursor, int* __restrict__ perm_src) {
    int stride = gridDim.x * blockDim.x;
    for (int k = blockIdx.x * blockDim.x + threadIdx.x; k < E; k += stride) {
        int j = dst[k];
        int p = offsets[j] + bsum[j >> BSHIFT] + atomicAdd(&cursor[j], 1);
        perm_src[p] = src[k];
    }
}
__global__ void gat_aggregate_f32_kernel(const float* __restrict__ feat_src,
                                         const float* __restrict__ el,
                                         const float* __restrict__ er,
                                         const int* __restrict__ offsets,
                                         const int* __restrict__ bsum,
                                         const int* __restrict__ counts,
                                         const int* __restrict__ perm_src,
                                         float* __restrict__ out, int Nd) {
    __shared__ float w_sh[CHUNK];
    __shared__ int   s_sh[CHUNK];
    __shared__ float red[2];
    int j = blockIdx.x;
    int tid = threadIdx.x;
    int cnt = counts[j];
    size_t orow = (size_t)j * D;
    if (cnt == 0) { out[orow + tid] = 0.0f; return; }
    int beg = offsets[j] + bsum[j >> BSHIFT];
    float erj = er[j];
    float acc = 0.0f;
    float inv;
    if (cnt <= CHUNK) {
        float lmax = -INFINITY;
        for (int t = tid; t < cnt; t += AGG_THREADS) {
            int s = perm_src[beg + t];
            float e = el[s] + erj;
            e = (e >= 0.0f) ? e : 0.01f * e;
            s_sh[t] = s; w_sh[t] = e;
            lmax = fmaxf(lmax, e);
        }
        float m = block_max128(lmax, red, tid);
        float lsum = 0.0f;
        for (int t = tid; t < cnt; t += AGG_THREADS) {
            float a = __expf(w_sh[t] - m);
            w_sh[t] = a; lsum += a;
        }
        float den = block_sum128(lsum, red, tid);
        inv = 1.0f / den;
        __syncthreads();
        for (int t = 0; t < cnt; ++t)
            acc += feat_src[(size_t)s_sh[t] * D + tid] * w_sh[t];
    } else {
        float lmax = -INFINITY;
        for (int t = tid; t < cnt; t += AGG_THREADS) {
            int s = perm_src[beg + t];
            float e = el[s] + erj;
            e = (e >= 0.0f) ? e : 0.01f * e;
            lmax = fmaxf(lmax, e);
        }
        float m = block_max128(lmax, red, tid);
        float lsum = 0.0f;
        for (int t = tid; t < cnt; t += AGG_THREADS) {
            int s = perm_src[beg + t];
            float e = el[s] + erj;
            e = (e >= 0.0f) ? e : 0.01f * e;
            lsum += __expf(e - m);
        }
        float den = block_sum128(lsum, red, tid);
        inv = 1.0f / den;
        for (int bb = 0; bb < cnt; bb += CHUNK) {
            int n = min(CHUNK, cnt - bb);
            __syncthreads();
            for (int t = tid; t < n; t += AGG_THREADS) {
                int s = perm_src[beg + bb + t];
                float e = el[s] + erj;
                e = (e >= 0.0f) ? e : 0.01f * e;
                s_sh[t] = s;
                w_sh[t] = __expf(e - m);
            }
            __syncthreads();
            for (int t = 0; t < n; ++t)
                acc += feat_src[(size_t)s_sh[t] * D + tid] * w_sh[t];
        }
    }
    out[orow + tid] = acc * inv;
}

extern "C" void kernel_launch(void* const* d_in, const int* in_sizes, int n_in,
                              void* d_out, int out_size, void* d_ws, size_t ws_size,
                              hipStream_t stream) {
    const float* feat_src = (const float*)d_in[0];
    const float* feat_dst = (const float*)d_in[1];
    const int*   src      = (const int*)d_in[2];
    const int*   dst      = (const int*)d_in[3];
    const float* attn_l   = (const float*)d_in[4];
    const float* attn_r   = (const float*)d_in[5];
    float* out = (float*)d_out;

    int Ns = in_sizes[0] / D;
    int Nd = in_sizes[1] / D;
    int E  = in_sizes[2];
    int NBK = (Nd + (1 << BSHIFT) - 1) >> BSHIFT;
    int NWG = (E + PCHUNK - 1) / PCHUNK;

    char* p = (char*)d_ws;
    auto carve = [&](size_t bytes) { void* r = (void*)p; p += (bytes + 255) & ~(size_t)255; return r; };
    float* el      = (float*)carve((size_t)Ns * 4);
    float* er      = (float*)carve((size_t)Nd * 4);
    int*   counts  = (int*)carve((size_t)Nd * 4);
    int*   offs    = (int*)carve((size_t)Nd * 4);       // fallback: 'offsets'
    int*   gcursor = (int*)carve((size_t)Nd * 4);       // fallback only
    int*   bsums   = (int*)carve((size_t)NBK * 4);      // fallback only
    int*   cnt_tab = (int*)carve((size_t)NWG * NBK * 4);
    int*   loc_tab = (int*)carve((size_t)NWG * NBK * 4);
    int*   perm    = (int*)carve((size_t)NBK * PR * 4); // >= E*4, shared w/ fallback
    uint2* bins    = (uint2*)carve((size_t)NWG * PCHUNK * 8);
    size_t used    = (size_t)(p - (char*)d_ws);
    size_t bf_bytes = (size_t)Ns * D * 2;
    unsigned short* feat_bf = (unsigned short*)carve(bf_bytes);

    int fast = (NBK <= MAXB && NWG <= MAXWG &&
                used + bf_bytes + 256 <= ws_size) ? 1 : 0;

    int total = Ns + Nd;
    int prep_blocks = (total + 7) / 8;
    if (fast) {
        // fused prep+partition: partition blocks first (issue early), prep after
        prep_partition_kernel<<<NWG + prep_blocks, 256, 0, stream>>>(
            feat_src, feat_dst, attn_l, attn_r, el, er, feat_bf, Ns, Nd,
            src, dst, E, NBK, NWG, bins, cnt_tab, loc_tab);
        bucket_kernel<<<NBK, 256, 0, stream>>>(bins, cnt_tab, loc_tab, NBK, NWG,
                                               counts, offs, perm, Nd);
        gat_aggregate_wave_kernel<<<(Nd + 3) / 4, 256, 0, stream>>>(feat_bf, el, er, offs,
                                                                    counts, perm, out, Nd);
    } else {
        hipMemsetAsync(counts, 0, (size_t)Nd * 4, stream);
        hipMemsetAsync(gcursor, 0, (size_t)Nd * 4, stream);
        prep_kernel<<<prep_blocks, 256, 0, stream>>>(feat_src, feat_dst, attn_l, attn_r,
                                                     el, er, nullptr, 0, Ns, Nd);
        hist_kernel<<<2048, 256, 0, stream>>>(dst, E, counts);
        scan1_kernel<<<NBK, 256, 0, stream>>>(counts, offs, bsums, Nd);
        scan2_kernel<<<1, 256, 0, stream>>>(bsums, NBK);
        fill_kernel<<<2048, 256, 0, stream>>>(src, dst, E, offs, bsums, gcursor, perm);
        gat_aggregate_f32_kernel<<<Nd, AGG_THREADS, 0, stream>>>(feat_src, el, er, offs,
                                                                 bsums, counts, perm, out, Nd);
    }
}

// Round 14
// 247.165 us; speedup vs baseline: 1.1195x; 1.0275x over previous
//
#include <hip/hip_runtime.h>
#include <hip/hip_bf16.h>
#include <math.h>

#define D 128
#define AGG_THREADS 128
#define CHUNK 512
#define BSHIFT 8                 // 256 dst nodes per bucket (R2/R12-verified best)
#define MAXB 512                 // max buckets (nbk=391 at Nd=100K)
#define MAXWG 1024               // max partition WGs (LDS arrays in bucket kernel)
#define PCHUNK 2048              // edges per partition WG (R13-verified)
#define PE 8                     // PCHUNK / 256
#define EBUF_CAP 5120            // LDS staging cap in bucket kernel (mean 4096, 16 sigma)
#define PR 8192                  // perm region stride per bucket (45 sigma)

// ---------- helpers ----------
__device__ __forceinline__ unsigned short f2bf(float f) {
    union { float f; unsigned int u; } c; c.f = f;
    unsigned int u = c.u;
    unsigned int r = (u + 0x7FFFu + ((u >> 16) & 1u)) >> 16;  // RNE
    return (unsigned short)r;
}
__device__ __forceinline__ void unpack2(unsigned int w, float& lo, float& hi) {
    union { unsigned int u; float f; } c;
    c.u = w << 16;          lo = c.f;
    c.u = w & 0xFFFF0000u;  hi = c.f;
}

// 8-wave parallel exclusive scan over arr[0..n) in LDS -> outp[0..n).
// Call with 512 threads; barriers inside; returns grand total.
__device__ __forceinline__ int scan8w(const int* __restrict__ arr, int* __restrict__ outp,
                                      int n, int tid, int* wsum8) {
    int wv = tid >> 6, lane = tid & 63;
    int nchunk = (n + 63) >> 6;
    int cpw = (nchunk + 7) >> 3;
    int c0 = wv * cpw, c1 = min(nchunk, c0 + cpw);
    int carry = 0;
    for (int c = c0; c < c1; ++c) {
        int i = (c << 6) + lane;
        int v = (i < n) ? arr[i] : 0;
        int x = v;
        #pragma unroll
        for (int off = 1; off < 64; off <<= 1) {
            int t = __shfl_up(x, off, 64);
            if (lane >= off) x += t;
        }
        if (i < n) outp[i] = x - v + carry;
        carry += __shfl(x, 63, 64);
    }
    if (lane == 0) wsum8[wv] = carry;
    __syncthreads();
    int wbase = 0;
    for (int u = 0; u < wv; ++u) wbase += wsum8[u];
    if (wbase) {
        for (int c = c0; c < c1; ++c) {
            int i = (c << 6) + lane;
            if (i < n) outp[i] += wbase;
        }
    }
    int tot = 0;
    #pragma unroll
    for (int u = 0; u < 8; ++u) tot += wsum8[u];
    __syncthreads();
    return tot;
}

// ---------- FUSED prep + partition: heterogeneous block roles (R13-verified) ----------
__global__ void prep_partition_kernel(const float* __restrict__ feat_src,
                                      const float* __restrict__ feat_dst,
                                      const float* __restrict__ attn_l,
                                      const float* __restrict__ attn_r,
                                      float* __restrict__ el, float* __restrict__ er,
                                      unsigned short* __restrict__ feat_bf,
                                      int Ns, int Nd,
                                      const int* __restrict__ src,
                                      const int* __restrict__ dst,
                                      int E, int nbk, int nwg,
                                      uint2* __restrict__ bins,
                                      int* __restrict__ cnt_tab,
                                      int* __restrict__ loc_tab) {
    __shared__ int hist[MAXB];
    __shared__ int lstart[MAXB];
    __shared__ int cursor[MAXB];
    __shared__ uint2 sbuf[PCHUNK];         // 16 KB; total LDS ~22 KB
    int tid = threadIdx.x;

    if ((int)blockIdx.x < nwg) {
        // ---------------- partition role ----------------
        int w = blockIdx.x;
        int e0 = w * PCHUNK;
        int e1 = min(E, e0 + PCHUNK);
        int n = e1 - e0;

        for (int i = tid; i < nbk; i += 256) hist[i] = 0;
        __syncthreads();

        int es[PE], ed[PE];
        #pragma unroll
        for (int k = 0; k < PE; ++k) {
            int idx = e0 + k * 256 + tid;
            if (idx < e1) {
                es[k] = src[idx];
                ed[k] = dst[idx];
                atomicAdd(&hist[ed[k] >> BSHIFT], 1);
            }
        }
        __syncthreads();

        // exclusive scan of hist[0..nbk) by wave 0, 64-wide chunks (nbk<=512: <=8)
        if (tid < 64) {
            int carry = 0;
            for (int c = 0; c < nbk; c += 64) {
                int i = c + tid;
                int v = (i < nbk) ? hist[i] : 0;
                int x = v;
                #pragma unroll
                for (int off = 1; off < 64; off <<= 1) {
                    int t = __shfl_up(x, off, 64);
                    if (tid >= off) x += t;
                }
                if (i < nbk) lstart[i] = x - v + carry;
                carry += __shfl(x, 63, 64);
            }
        }
        __syncthreads();

        for (int i = tid; i < nbk; i += 256) {
            cnt_tab[(size_t)w * nbk + i] = hist[i];
            loc_tab[(size_t)w * nbk + i] = lstart[i];
            cursor[i] = 0;
        }
        __syncthreads();

        #pragma unroll
        for (int k = 0; k < PE; ++k) {
            int idx = e0 + k * 256 + tid;
            if (idx < e1) {
                int b = ed[k] >> BSHIFT;
                int r = lstart[b] + atomicAdd(&cursor[b], 1);
                sbuf[r] = make_uint2((unsigned)es[k], (unsigned)ed[k]);
            }
        }
        __syncthreads();

        uint2* obase = bins + (size_t)w * PCHUNK;
        for (int t = tid; t < n; t += 256) obase[t] = sbuf[t];   // coalesced
    } else {
        // ---------------- prep role ----------------
        int half = tid >> 5;               // 0..7 (8 rows per 256-thread block)
        int lane = tid & 31;
        int node = ((int)blockIdx.x - nwg) * 8 + half;
        if (node >= Ns + Nd) return;
        bool is_src = node < Ns;
        const float* feat = is_src ? feat_src + (size_t)node * D
                                   : feat_dst + (size_t)(node - Ns) * D;
        const float* attn = is_src ? attn_l : attn_r;
        float4 a = ((const float4*)attn)[lane];
        float4 v = ((const float4*)feat)[lane];
        if (is_src) {
            ushort4 h; h.x = f2bf(v.x); h.y = f2bf(v.y); h.z = f2bf(v.z); h.w = f2bf(v.w);
            ((ushort4*)(feat_bf + (size_t)node * D))[lane] = h;
        }
        float s = v.x * a.x + v.y * a.y + v.z * a.z + v.w * a.w;
        #pragma unroll
        for (int off = 16; off > 0; off >>= 1)
            s += __shfl_xor(s, off, 64);   // xor<=16 stays within each 32-lane half
        if (lane == 0) {
            if (is_src) el[node] = s;
            else        er[node - Ns] = s;
        }
    }
}

// ---------- standalone prep (fallback path only) ----------
__global__ void prep_kernel(const float* __restrict__ feat_src,
                            const float* __restrict__ feat_dst,
                            const float* __restrict__ attn_l,
                            const float* __restrict__ attn_r,
                            float* __restrict__ el, float* __restrict__ er,
                            unsigned short* __restrict__ feat_bf, int store_bf,
                            int Ns, int Nd) {
    int half = threadIdx.x >> 5;
    int lane = threadIdx.x & 31;
    int node = blockIdx.x * 8 + half;
    if (node >= Ns + Nd) return;
    bool is_src = node < Ns;
    const float* feat = is_src ? feat_src + (size_t)node * D
                               : feat_dst + (size_t)(node - Ns) * D;
    const float* attn = is_src ? attn_l : attn_r;
    float4 a = ((const float4*)attn)[lane];
    float4 v = ((const float4*)feat)[lane];
    if (is_src && store_bf) {
        ushort4 h; h.x = f2bf(v.x); h.y = f2bf(v.y); h.z = f2bf(v.z); h.w = f2bf(v.w);
        ((ushort4*)(feat_bf + (size_t)node * D))[lane] = h;
    }
    float s = v.x * a.x + v.y * a.y + v.z * a.z + v.w * a.w;
    #pragma unroll
    for (int off = 16; off > 0; off >>= 1)
        s += __shfl_xor(s, off, 64);
    if (lane == 0) {
        if (is_src) el[node] = s;
        else        er[node - Ns] = s;
    }
}

// ---------- bucket kernel: 512 threads (8 waves), shortened critical path ----------
// One 512-thread block per bucket (~4096 edges). Grid is small (391 blocks,
// 1.5/CU, fully resident) so makespan == per-block latency; 8 waves halve the
// gather/rank trip counts and wave-parallel scans replace serial/barrier scans.
__global__ void bucket_kernel(const uint2* __restrict__ bins,
                              const int* __restrict__ cnt_tab, const int* __restrict__ loc_tab,
                              int nbk, int nwg,
                              int* __restrict__ counts, int* __restrict__ offs,
                              int* __restrict__ perm, int Nd) {
    __shared__ uint2 ebuf[EBUF_CAP];       // 40 KB
    __shared__ int wcnt[MAXWG];
    __shared__ int wdst[MAXWG];
    __shared__ int sbase[MAXWG];
    __shared__ int cnt256[256];
    __shared__ int off256[256];
    __shared__ int cur256[256];
    __shared__ int wsum8[8];

    int b = blockIdx.x, tid = threadIdx.x;
    int base = b << BSHIFT;

    for (int i = tid; i < nwg; i += 512) wcnt[i] = cnt_tab[(size_t)i * nbk + b];
    if (tid < 256) { cnt256[tid] = 0; cur256[tid] = 0; }
    __syncthreads();

    // 8-wave exclusive scan over nwg segment counts
    int n = scan8w(wcnt, wdst, nwg, tid, wsum8);
    bool fits = (n <= EBUF_CAP);

    for (int w = tid; w < nwg; w += 512)
        sbase[w] = w * PCHUNK + loc_tab[(size_t)w * nbk + b] - wdst[w];
    __syncthreads();

    if (fits) {
        // per-edge parallel gather: seg id via binary search in wdst
        for (int t = tid; t < n; t += 512) {
            int lo = 0, hi = nwg - 1;
            while (lo < hi) {              // last w with wdst[w] <= t
                int mid = (lo + hi + 1) >> 1;
                if (wdst[mid] <= t) lo = mid; else hi = mid - 1;
            }
            uint2 e = bins[(size_t)(sbase[lo] + t)];
            ebuf[t] = e;
            atomicAdd(&cnt256[(int)e.y - base], 1);
        }
    } else {
        // slow path (statistically unreachable): count straight from global
        for (int w = tid; w < nwg; w += 512) {
            int c = wcnt[w];
            const uint2* sp = bins + (size_t)(sbase[w] + wdst[w]);
            for (int k = 0; k < c; ++k)
                atomicAdd(&cnt256[(int)sp[k].y - base], 1);
        }
    }
    __syncthreads();

    // wave-parallel exclusive scan of the 256 per-dst counts (2 barriers)
    scan8w(cnt256, off256, 256, tid, wsum8);
    if (tid < 256) {
        int v = cnt256[tid];
        int myoff = off256[tid];
        int i = base + tid;
        if (i < Nd) {
            int c = v;
            if (myoff + c > PR) c = max(0, PR - myoff);   // paranoia clamp
            counts[i] = c;
            offs[i]   = myoff;
        }
    }
    __syncthreads();

    // rank + write perm into this bucket's fixed region
    size_t rbase = (size_t)b * PR;
    if (fits) {
        for (int t = tid; t < n; t += 512) {
            uint2 e = ebuf[t];
            int d = (int)e.y - base;
            int r = atomicAdd(&cur256[d], 1);
            int slot = off256[d] + r;
            if (slot < PR) perm[rbase + slot] = (int)e.x;
        }
    } else {
        for (int w = tid; w < nwg; w += 512) {
            int c = wcnt[w];
            const uint2* sp = bins + (size_t)(sbase[w] + wdst[w]);
            for (int k = 0; k < c; ++k) {
                uint2 e = sp[k];
                int d = (int)e.y - base;
                int r = atomicAdd(&cur256[d], 1);
                int slot = off256[d] + r;
                if (slot < PR) perm[rbase + slot] = (int)e.x;
            }
        }
    }
}

// ---------- block reductions (128 threads = 2 waves) for fallback aggregate ----------
__device__ __forceinline__ float block_max128(float v, float* red, int tid) {
    #pragma unroll
    for (int off = 32; off > 0; off >>= 1)
        v = fmaxf(v, __shfl_down(v, off, 64));
    __syncthreads();
    if ((tid & 63) == 0) red[tid >> 6] = v;
    __syncthreads();
    return fmaxf(red[0], red[1]);
}
__device__ __forceinline__ float block_sum128(float v, float* red, int tid) {
    #pragma unroll
    for (int off = 32; off > 0; off >>= 1)
        v += __shfl_down(v, off, 64);
    __syncthreads();
    if ((tid & 63) == 0) red[tid >> 6] = v;
    __syncthreads();
    return red[0] + red[1];
}

// ---------- wave-per-dst bf16 aggregate: no LDS, no barriers, 2-deep pipeline ----------
__global__ void gat_aggregate_wave_kernel(const unsigned short* __restrict__ feat_bf,
                                          const float* __restrict__ el,
                                          const float* __restrict__ er,
                                          const int* __restrict__ offs,
                                          const int* __restrict__ counts,
                                          const int* __restrict__ perm,
                                          float* __restrict__ out, int Nd) {
    int wid  = threadIdx.x >> 6;           // wave in block: 0..3
    int lane = threadIdx.x & 63;
    int j = blockIdx.x * 4 + wid;
    if (j >= Nd) return;
    int cnt = counts[j];
    size_t orow = (size_t)j * D;
    if (cnt == 0) {
        ((float2*)(out + orow))[lane] = make_float2(0.0f, 0.0f);  // 64 x 8B = 512B
        return;
    }
    size_t beg = (size_t)(j >> BSHIFT) * PR + (size_t)offs[j];
    float erj = er[j];
    int sg = lane >> 4, u = lane & 15;
    const unsigned short* fb = feat_bf + (size_t)u * 8;
    float acc[8];
    #pragma unroll
    for (int k = 0; k < 8; ++k) acc[k] = 0.0f;

    if (cnt <= 64) {
        // one edge per lane, everything in registers
        int s = 0; float e = -INFINITY;
        if (lane < cnt) {
            s = perm[beg + lane];
            float t = el[s] + erj;
            e = (t >= 0.0f) ? t : 0.01f * t;   // leaky_relu
        }
        float m = e;
        #pragma unroll
        for (int off = 32; off > 0; off >>= 1)
            m = fmaxf(m, __shfl_xor(m, off, 64));
        float a = (lane < cnt) ? __expf(e - m) : 0.0f;
        float den = a;
        #pragma unroll
        for (int off = 32; off > 0; off >>= 1)
            den += __shfl_xor(den, off, 64);
        a *= (1.0f / den);                      // pre-normalized weight
        int nit = (cnt + 3) >> 2;               // uniform trip count for all lanes
        int it = 0;
        for (; it + 2 <= nit; it += 2) {        // 2-deep: two rows in flight
            int t0 = sg + (it << 2);            // t0 < cnt guaranteed in this loop
            int t1 = t0 + 4;
            int u1 = (t1 < cnt) ? t1 : 0;
            float w0 = __shfl(a, t0, 64);
            int   s0 = __shfl(s, t0, 64);
            float w1 = __shfl(a, u1, 64);
            int   s1 = __shfl(s, u1, 64);
            bool p1 = (t1 < cnt);
            uint4 v0 = *(const uint4*)(fb + (size_t)s0 * D);
            uint4 v1 = p1 ? *(const uint4*)(fb + (size_t)s1 * D) : make_uint4(0,0,0,0);
            float f[8];
            unpack2(v0.x, f[0], f[1]); unpack2(v0.y, f[2], f[3]);
            unpack2(v0.z, f[4], f[5]); unpack2(v0.w, f[6], f[7]);
            #pragma unroll
            for (int k = 0; k < 8; ++k) acc[k] += w0 * f[k];
            if (p1) {
                unpack2(v1.x, f[0], f[1]); unpack2(v1.y, f[2], f[3]);
                unpack2(v1.z, f[4], f[5]); unpack2(v1.w, f[6], f[7]);
                #pragma unroll
                for (int k = 0; k < 8; ++k) acc[k] += w1 * f[k];
            }
        }
        if (it < nit) {                         // tail
            int t0 = sg + (it << 2);
            int u0 = (t0 < cnt) ? t0 : 0;
            float w0 = __shfl(a, u0, 64);
            int   s0 = __shfl(s, u0, 64);
            if (t0 < cnt) {
                uint4 v0 = *(const uint4*)(fb + (size_t)s0 * D);
                float f[8];
                unpack2(v0.x, f[0], f[1]); unpack2(v0.y, f[2], f[3]);
                unpack2(v0.z, f[4], f[5]); unpack2(v0.w, f[6], f[7]);
                #pragma unroll
                for (int k = 0; k < 8; ++k) acc[k] += w0 * f[k];
            }
        }
    } else {
        // chunked recompute path (cnt > 64)
        float lmax = -INFINITY;
        for (int t = lane; t < cnt; t += 64) {
            int s = perm[beg + t];
            float e = el[s] + erj;
            e = (e >= 0.0f) ? e : 0.01f * e;
            lmax = fmaxf(lmax, e);
        }
        float m = lmax;
        #pragma unroll
        for (int off = 32; off > 0; off >>= 1)
            m = fmaxf(m, __shfl_xor(m, off, 64));
        float lsum = 0.0f;
        for (int t = lane; t < cnt; t += 64) {
            int s = perm[beg + t];
            float e = el[s] + erj;
            e = (e >= 0.0f) ? e : 0.01f * e;
            lsum += __expf(e - m);
        }
        #pragma unroll
        for (int off = 32; off > 0; off >>= 1)
            lsum += __shfl_xor(lsum, off, 64);
        float inv = 1.0f / lsum;
        for (int bb = 0; bb < cnt; bb += 64) {
            int nn = min(64, cnt - bb);
            int s = 0; float a = 0.0f;
            if (lane < nn) {
                s = perm[beg + bb + lane];
                float e = el[s] + erj;
                e = (e >= 0.0f) ? e : 0.01f * e;
                a = __expf(e - m) * inv;
            }
            int nit = (nn + 3) >> 2;            // uniform trip count
            for (int it = 0; it < nit; ++it) {
                int t = sg + (it << 2);
                int tt = (t < nn) ? t : 0;
                float w = __shfl(a, tt, 64);
                int st  = __shfl(s, tt, 64);
                if (t < nn) {
                    uint4 v = *(const uint4*)(fb + (size_t)st * D);
                    float f[8];
                    unpack2(v.x, f[0], f[1]); unpack2(v.y, f[2], f[3]);
                    unpack2(v.z, f[4], f[5]); unpack2(v.w, f[6], f[7]);
                    #pragma unroll
                    for (int k = 0; k < 8; ++k) acc[k] += w * f[k];
                }
            }
        }
    }
    // reduce across the 4 subgroups (lane bits 4,5) — all 64 lanes active here
    #pragma unroll
    for (int k = 0; k < 8; ++k) {
        acc[k] += __shfl_xor(acc[k], 16, 64);
        acc[k] += __shfl_xor(acc[k], 32, 64);
    }
    if (sg == 0) {
        float* op = out + orow + (size_t)u * 8;
        ((float4*)op)[0] = make_float4(acc[0], acc[1], acc[2], acc[3]);
        ((float4*)op)[1] = make_float4(acc[4], acc[5], acc[6], acc[7]);
    }
}

// ================= fallback pipeline (only if workspace too small) =================
__global__ void hist_kernel(const int* __restrict__ dst, int E, int* __restrict__ counts) {
    int stride = gridDim.x * blockDim.x;
    for (int k = blockIdx.x * blockDim.x + threadIdx.x; k < E; k += stride)
        atomicAdd(&counts[dst[k]], 1);
}
__global__ void scan1_kernel(const int* __restrict__ counts, int* __restrict__ offsets,
                             int* __restrict__ blockSums, int N) {
    __shared__ int tile[256];
    int tid = threadIdx.x;
    int i = blockIdx.x * 256 + tid;
    int v = (i < N) ? counts[i] : 0;
    tile[tid] = v;
    __syncthreads();
    for (int off = 1; off < 256; off <<= 1) {
        int t = (tid >= off) ? tile[tid - off] : 0;
        __syncthreads();
        tile[tid] += t;
        __syncthreads();
    }
    int incl = tile[tid];
    if (i < N) offsets[i] = incl - v;
    if (tid == 255) blockSums[blockIdx.x] = incl;
}
__global__ void scan2_kernel(int* __restrict__ bs, int nb) {
    __shared__ int tile[256];
    int tid = threadIdx.x;
    int carry = 0;
    for (int base = 0; base < nb; base += 256) {
        int i = base + tid;
        int v = (i < nb) ? bs[i] : 0;
        __syncthreads();
        tile[tid] = v;
        __syncthreads();
        for (int off = 1; off < 256; off <<= 1) {
            int t = (tid >= off) ? tile[tid - off] : 0;
            __syncthreads();
            tile[tid] += t;
            __syncthreads();
        }
        int incl = tile[tid];
        if (i < nb) bs[i] = incl - v + carry;
        carry += tile[255];
    }
}
__global__ void fill_kernel(const int* __restrict__ src, const int* __restrict__ dst, int E,
                            const int* __restrict__ offsets, const int* __restrict__ bsum,
                            int* __restrict__ cursor, int* __restrict__ perm_src) {
    int stride = gridDim.x * blockDim.x;
    for (int k = blockIdx.x * blockDim.x + threadIdx.x; k < E; k += stride) {
        int j = dst[k];
        int p = offsets[j] + bsum[j >> BSHIFT] + atomicAdd(&cursor[j], 1);
        perm_src[p] = src[k];
    }
}
__global__ void gat_aggregate_f32_kernel(const float* __restrict__ feat_src,
                                         const float* __restrict__ el,
                                         const float* __restrict__ er,
                                         const int* __restrict__ offsets,
                                         const int* __restrict__ bsum,
                                         const int* __restrict__ counts,
                                         const int* __restrict__ perm_src,
                                         float* __restrict__ out, int Nd) {
    __shared__ float w_sh[CHUNK];
    __shared__ int   s_sh[CHUNK];
    __shared__ float red[2];
    int j = blockIdx.x;
    int tid = threadIdx.x;
    int cnt = counts[j];
    size_t orow = (size_t)j * D;
    if (cnt == 0) { out[orow + tid] = 0.0f; return; }
    int beg = offsets[j] + bsum[j >> BSHIFT];
    float erj = er[j];
    float acc = 0.0f;
    float inv;
    if (cnt <= CHUNK) {
        float lmax = -INFINITY;
        for (int t = tid; t < cnt; t += AGG_THREADS) {
            int s = perm_src[beg + t];
            float e = el[s] + erj;
            e = (e >= 0.0f) ? e : 0.01f * e;
            s_sh[t] = s; w_sh[t] = e;
            lmax = fmaxf(lmax, e);
        }
        float m = block_max128(lmax, red, tid);
        float lsum = 0.0f;
        for (int t = tid; t < cnt; t += AGG_THREADS) {
            float a = __expf(w_sh[t] - m);
            w_sh[t] = a; lsum += a;
        }
        float den = block_sum128(lsum, red, tid);
        inv = 1.0f / den;
        __syncthreads();
        for (int t = 0; t < cnt; ++t)
            acc += feat_src[(size_t)s_sh[t] * D + tid] * w_sh[t];
    } else {
        float lmax = -INFINITY;
        for (int t = tid; t < cnt; t += AGG_THREADS) {
            int s = perm_src[beg + t];
            float e = el[s] + erj;
            e = (e >= 0.0f) ? e : 0.01f * e;
            lmax = fmaxf(lmax, e);
        }
        float m = block_max128(lmax, red, tid);
        float lsum = 0.0f;
        for (int t = tid; t < cnt; t += AGG_THREADS) {
            int s = perm_src[beg + t];
            float e = el[s] + erj;
            e = (e >= 0.0f) ? e : 0.01f * e;
            lsum += __expf(e - m);
        }
        float den = block_sum128(lsum, red, tid);
        inv = 1.0f / den;
        for (int bb = 0; bb < cnt; bb += CHUNK) {
            int n = min(CHUNK, cnt - bb);
            __syncthreads();
            for (int t = tid; t < n; t += AGG_THREADS) {
                int s = perm_src[beg + bb + t];
                float e = el[s] + erj;
                e = (e >= 0.0f) ? e : 0.01f * e;
                s_sh[t] = s;
                w_sh[t] = __expf(e - m);
            }
            __syncthreads();
            for (int t = 0; t < n; ++t)
                acc += feat_src[(size_t)s_sh[t] * D + tid] * w_sh[t];
        }
    }
    out[orow + tid] = acc * inv;
}

extern "C" void kernel_launch(void* const* d_in, const int* in_sizes, int n_in,
                              void* d_out, int out_size, void* d_ws, size_t ws_size,
                              hipStream_t stream) {
    const float* feat_src = (const float*)d_in[0];
    const float* feat_dst = (const float*)d_in[1];
    const int*   src      = (const int*)d_in[2];
    const int*   dst      = (const int*)d_in[3];
    const float* attn_l   = (const float*)d_in[4];
    const float* attn_r   = (const float*)d_in[5];
    float* out = (float*)d_out;

    int Ns = in_sizes[0] / D;
    int Nd = in_sizes[1] / D;
    int E  = in_sizes[2];
    int NBK = (Nd + (1 << BSHIFT) - 1) >> BSHIFT;
    int NWG = (E + PCHUNK - 1) / PCHUNK;

    char* p = (char*)d_ws;
    auto carve = [&](size_t bytes) { void* r = (void*)p; p += (bytes + 255) & ~(size_t)255; return r; };
    float* el      = (float*)carve((size_t)Ns * 4);
    float* er      = (float*)carve((size_t)Nd * 4);
    int*   counts  = (int*)carve((size_t)Nd * 4);
    int*   offs    = (int*)carve((size_t)Nd * 4);       // fallback: 'offsets'
    int*   gcursor = (int*)carve((size_t)Nd * 4);       // fallback only
    int*   bsums   = (int*)carve((size_t)NBK * 4);      // fallback only
    int*   cnt_tab = (int*)carve((size_t)NWG * NBK * 4);
    int*   loc_tab = (int*)carve((size_t)NWG * NBK * 4);
    int*   perm    = (int*)carve((size_t)NBK * PR * 4); // >= E*4, shared w/ fallback
    uint2* bins    = (uint2*)carve((size_t)NWG * PCHUNK * 8);
    size_t used    = (size_t)(p - (char*)d_ws);
    size_t bf_bytes = (size_t)Ns * D * 2;
    unsigned short* feat_bf = (unsigned short*)carve(bf_bytes);

    int fast = (NBK <= MAXB && NWG <= MAXWG &&
                used + bf_bytes + 256 <= ws_size) ? 1 : 0;

    int total = Ns + Nd;
    int prep_blocks = (total + 7) / 8;
    if (fast) {
        // fused prep+partition: partition blocks first (issue early), prep after
        prep_partition_kernel<<<NWG + prep_blocks, 256, 0, stream>>>(
            feat_src, feat_dst, attn_l, attn_r, el, er, feat_bf, Ns, Nd,
            src, dst, E, NBK, NWG, bins, cnt_tab, loc_tab);
        bucket_kernel<<<NBK, 512, 0, stream>>>(bins, cnt_tab, loc_tab, NBK, NWG,
                                               counts, offs, perm, Nd);
        gat_aggregate_wave_kernel<<<(Nd + 3) / 4, 256, 0, stream>>>(feat_bf, el, er, offs,
                                                                    counts, perm, out, Nd);
    } else {
        hipMemsetAsync(counts, 0, (size_t)Nd * 4, stream);
        hipMemsetAsync(gcursor, 0, (size_t)Nd * 4, stream);
        prep_kernel<<<prep_blocks, 256, 0, stream>>>(feat_src, feat_dst, attn_l, attn_r,
                                                     el, er, nullptr, 0, Ns, Nd);
        hist_kernel<<<2048, 256, 0, stream>>>(dst, E, counts);
        scan1_kernel<<<NBK, 256, 0, stream>>>(counts, offs, bsums, Nd);
        scan2_kernel<<<1, 256, 0, stream>>>(bsums, NBK);
        fill_kernel<<<2048, 256, 0, stream>>>(src, dst, E, offs, bsums, gcursor, perm);
        gat_aggregate_f32_kernel<<<Nd, AGG_THREADS, 0, stream>>>(feat_src, el, er, offs,
                                                                 bsums, counts, perm, out, Nd);
    }
}

// Round 15
// 243.612 us; speedup vs baseline: 1.1358x; 1.0146x over previous
//
#include <hip/hip_runtime.h>
#include <hip/hip_bf16.h>
#include <math.h>

#define D 128
#define AGG_THREADS 128
#define CHUNK 512
#define BSHIFT 8                 // 256 dst nodes per bucket (R2/R12-verified best)
#define MAXB 512                 // max buckets (nbk=391 at Nd=100K)
#define MAXWG 1024               // max partition WGs (LDS arrays in bucket kernel)
#define PCHUNK 2048              // edges per partition WG (R13-verified)
#define PE 8                     // PCHUNK / 256
#define EBUF_CAP 5120            // LDS staging cap in bucket kernel (mean 4096, 16 sigma)
#define PR 8192                  // perm region stride per bucket (45 sigma)

// ---------- helpers ----------
__device__ __forceinline__ unsigned short f2bf(float f) {
    union { float f; unsigned int u; } c; c.f = f;
    unsigned int u = c.u;
    unsigned int r = (u + 0x7FFFu + ((u >> 16) & 1u)) >> 16;  // RNE
    return (unsigned short)r;
}
__device__ __forceinline__ void unpack2(unsigned int w, float& lo, float& hi) {
    union { unsigned int u; float f; } c;
    c.u = w << 16;          lo = c.f;
    c.u = w & 0xFFFF0000u;  hi = c.f;
}

// 8-wave parallel exclusive scan over arr[0..n) in LDS -> outp[0..n).
// Call with 512 threads; barriers inside; returns grand total.
__device__ __forceinline__ int scan8w(const int* __restrict__ arr, int* __restrict__ outp,
                                      int n, int tid, int* wsum8) {
    int wv = tid >> 6, lane = tid & 63;
    int nchunk = (n + 63) >> 6;
    int cpw = (nchunk + 7) >> 3;
    int c0 = wv * cpw, c1 = min(nchunk, c0 + cpw);
    int carry = 0;
    for (int c = c0; c < c1; ++c) {
        int i = (c << 6) + lane;
        int v = (i < n) ? arr[i] : 0;
        int x = v;
        #pragma unroll
        for (int off = 1; off < 64; off <<= 1) {
            int t = __shfl_up(x, off, 64);
            if (lane >= off) x += t;
        }
        if (i < n) outp[i] = x - v + carry;
        carry += __shfl(x, 63, 64);
    }
    if (lane == 0) wsum8[wv] = carry;
    __syncthreads();
    int wbase = 0;
    for (int u = 0; u < wv; ++u) wbase += wsum8[u];
    if (wbase) {
        for (int c = c0; c < c1; ++c) {
            int i = (c << 6) + lane;
            if (i < n) outp[i] += wbase;
        }
    }
    int tot = 0;
    #pragma unroll
    for (int u = 0; u < 8; ++u) tot += wsum8[u];
    __syncthreads();
    return tot;
}

// ---------- FUSED prep + partition: heterogeneous block roles (R13-verified) ----------
__global__ void prep_partition_kernel(const float* __restrict__ feat_src,
                                      const float* __restrict__ feat_dst,
                                      const float* __restrict__ attn_l,
                                      const float* __restrict__ attn_r,
                                      float* __restrict__ el, float* __restrict__ er,
                                      unsigned short* __restrict__ feat_bf,
                                      int Ns, int Nd,
                                      const int* __restrict__ src,
                                      const int* __restrict__ dst,
                                      int E, int nbk, int nwg,
                                      uint2* __restrict__ bins,
                                      int* __restrict__ cnt_tab,
                                      int* __restrict__ loc_tab) {
    __shared__ int hist[MAXB];
    __shared__ int lstart[MAXB];
    __shared__ int cursor[MAXB];
    __shared__ uint2 sbuf[PCHUNK];         // 16 KB; total LDS ~22 KB
    int tid = threadIdx.x;

    if ((int)blockIdx.x < nwg) {
        // ---------------- partition role ----------------
        int w = blockIdx.x;
        int e0 = w * PCHUNK;
        int e1 = min(E, e0 + PCHUNK);
        int n = e1 - e0;

        for (int i = tid; i < nbk; i += 256) hist[i] = 0;
        __syncthreads();

        int es[PE], ed[PE];
        #pragma unroll
        for (int k = 0; k < PE; ++k) {
            int idx = e0 + k * 256 + tid;
            if (idx < e1) {
                es[k] = src[idx];
                ed[k] = dst[idx];
                atomicAdd(&hist[ed[k] >> BSHIFT], 1);
            }
        }
        __syncthreads();

        // exclusive scan of hist[0..nbk) by wave 0, 64-wide chunks (nbk<=512: <=8)
        if (tid < 64) {
            int carry = 0;
            for (int c = 0; c < nbk; c += 64) {
                int i = c + tid;
                int v = (i < nbk) ? hist[i] : 0;
                int x = v;
                #pragma unroll
                for (int off = 1; off < 64; off <<= 1) {
                    int t = __shfl_up(x, off, 64);
                    if (tid >= off) x += t;
                }
                if (i < nbk) lstart[i] = x - v + carry;
                carry += __shfl(x, 63, 64);
            }
        }
        __syncthreads();

        for (int i = tid; i < nbk; i += 256) {
            cnt_tab[(size_t)w * nbk + i] = hist[i];
            loc_tab[(size_t)w * nbk + i] = lstart[i];
            cursor[i] = 0;
        }
        __syncthreads();

        #pragma unroll
        for (int k = 0; k < PE; ++k) {
            int idx = e0 + k * 256 + tid;
            if (idx < e1) {
                int b = ed[k] >> BSHIFT;
                int r = lstart[b] + atomicAdd(&cursor[b], 1);
                sbuf[r] = make_uint2((unsigned)es[k], (unsigned)ed[k]);
            }
        }
        __syncthreads();

        uint2* obase = bins + (size_t)w * PCHUNK;
        for (int t = tid; t < n; t += 256) obase[t] = sbuf[t];   // coalesced
    } else {
        // ---------------- prep role ----------------
        int half = tid >> 5;               // 0..7 (8 rows per 256-thread block)
        int lane = tid & 31;
        int node = ((int)blockIdx.x - nwg) * 8 + half;
        if (node >= Ns + Nd) return;
        bool is_src = node < Ns;
        const float* feat = is_src ? feat_src + (size_t)node * D
                                   : feat_dst + (size_t)(node - Ns) * D;
        const float* attn = is_src ? attn_l : attn_r;
        float4 a = ((const float4*)attn)[lane];
        float4 v = ((const float4*)feat)[lane];
        if (is_src) {
            ushort4 h; h.x = f2bf(v.x); h.y = f2bf(v.y); h.z = f2bf(v.z); h.w = f2bf(v.w);
            ((ushort4*)(feat_bf + (size_t)node * D))[lane] = h;
        }
        float s = v.x * a.x + v.y * a.y + v.z * a.z + v.w * a.w;
        #pragma unroll
        for (int off = 16; off > 0; off >>= 1)
            s += __shfl_xor(s, off, 64);   // xor<=16 stays within each 32-lane half
        if (lane == 0) {
            if (is_src) el[node] = s;
            else        er[node - Ns] = s;
        }
    }
}

// ---------- standalone prep (fallback path only) ----------
__global__ void prep_kernel(const float* __restrict__ feat_src,
                            const float* __restrict__ feat_dst,
                            const float* __restrict__ attn_l,
                            const float* __restrict__ attn_r,
                            float* __restrict__ el, float* __restrict__ er,
                            unsigned short* __restrict__ feat_bf, int store_bf,
                            int Ns, int Nd) {
    int half = threadIdx.x >> 5;
    int lane = threadIdx.x & 31;
    int node = blockIdx.x * 8 + half;
    if (node >= Ns + Nd) return;
    bool is_src = node < Ns;
    const float* feat = is_src ? feat_src + (size_t)node * D
                               : feat_dst + (size_t)(node - Ns) * D;
    const float* attn = is_src ? attn_l : attn_r;
    float4 a = ((const float4*)attn)[lane];
    float4 v = ((const float4*)feat)[lane];
    if (is_src && store_bf) {
        ushort4 h; h.x = f2bf(v.x); h.y = f2bf(v.y); h.z = f2bf(v.z); h.w = f2bf(v.w);
        ((ushort4*)(feat_bf + (size_t)node * D))[lane] = h;
    }
    float s = v.x * a.x + v.y * a.y + v.z * a.z + v.w * a.w;
    #pragma unroll
    for (int off = 16; off > 0; off >>= 1)
        s += __shfl_xor(s, off, 64);
    if (lane == 0) {
        if (is_src) el[node] = s;
        else        er[node - Ns] = s;
    }
}

// ---------- bucket kernel: 512 threads, direct per-segment copy (no binary search) ----------
// One 512-thread block per bucket (~4096 edges, ~782 segments, mean 5.2 edges/seg).
// Each thread walks ~1.5 segments; loads have affine addresses (independent,
// compiler-pipelined) -- replaces the 10-step dependent binary search per edge.
__global__ void bucket_kernel(const uint2* __restrict__ bins,
                              const int* __restrict__ cnt_tab, const int* __restrict__ loc_tab,
                              int nbk, int nwg,
                              int* __restrict__ counts, int* __restrict__ offs,
                              int* __restrict__ perm, int Nd) {
    __shared__ uint2 ebuf[EBUF_CAP];       // 40 KB
    __shared__ int wcnt[MAXWG];
    __shared__ int wdst[MAXWG];
    __shared__ int sbase[MAXWG];
    __shared__ int cnt256[256];
    __shared__ int off256[256];
    __shared__ int cur256[256];
    __shared__ int wsum8[8];

    int b = blockIdx.x, tid = threadIdx.x;
    int base = b << BSHIFT;

    for (int i = tid; i < nwg; i += 512) wcnt[i] = cnt_tab[(size_t)i * nbk + b];
    if (tid < 256) { cnt256[tid] = 0; cur256[tid] = 0; }
    __syncthreads();

    // 8-wave exclusive scan over nwg segment counts
    int n = scan8w(wcnt, wdst, nwg, tid, wsum8);
    bool fits = (n <= EBUF_CAP);

    for (int w = tid; w < nwg; w += 512)
        sbase[w] = w * PCHUNK + loc_tab[(size_t)w * nbk + b] - wdst[w];
    __syncthreads();

    if (fits) {
        // direct per-segment gather into LDS at the scanned offset; count fused
        for (int w = tid; w < nwg; w += 512) {
            int c = wcnt[w];
            if (c) {
                const uint2* sp = bins + (size_t)(sbase[w] + wdst[w]);
                int d0 = wdst[w];
                for (int k = 0; k < c; ++k) {
                    uint2 e = sp[k];
                    ebuf[d0 + k] = e;
                    atomicAdd(&cnt256[(int)e.y - base], 1);
                }
            }
        }
    } else {
        // slow path (statistically unreachable): count straight from global
        for (int w = tid; w < nwg; w += 512) {
            int c = wcnt[w];
            const uint2* sp = bins + (size_t)(sbase[w] + wdst[w]);
            for (int k = 0; k < c; ++k)
                atomicAdd(&cnt256[(int)sp[k].y - base], 1);
        }
    }
    __syncthreads();

    // wave-parallel exclusive scan of the 256 per-dst counts (2 barriers)
    scan8w(cnt256, off256, 256, tid, wsum8);
    if (tid < 256) {
        int v = cnt256[tid];
        int myoff = off256[tid];
        int i = base + tid;
        if (i < Nd) {
            int c = v;
            if (myoff + c > PR) c = max(0, PR - myoff);   // paranoia clamp
            counts[i] = c;
            offs[i]   = myoff;
        }
    }
    __syncthreads();

    // rank + write perm into this bucket's fixed region
    size_t rbase = (size_t)b * PR;
    if (fits) {
        for (int t = tid; t < n; t += 512) {
            uint2 e = ebuf[t];
            int d = (int)e.y - base;
            int r = atomicAdd(&cur256[d], 1);
            int slot = off256[d] + r;
            if (slot < PR) perm[rbase + slot] = (int)e.x;
        }
    } else {
        for (int w = tid; w < nwg; w += 512) {
            int c = wcnt[w];
            const uint2* sp = bins + (size_t)(sbase[w] + wdst[w]);
            for (int k = 0; k < c; ++k) {
                uint2 e = sp[k];
                int d = (int)e.y - base;
                int r = atomicAdd(&cur256[d], 1);
                int slot = off256[d] + r;
                if (slot < PR) perm[rbase + slot] = (int)e.x;
            }
        }
    }
}

// ---------- block reductions (128 threads = 2 waves) for fallback aggregate ----------
__device__ __forceinline__ float block_max128(float v, float* red, int tid) {
    #pragma unroll
    for (int off = 32; off > 0; off >>= 1)
        v = fmaxf(v, __shfl_down(v, off, 64));
    __syncthreads();
    if ((tid & 63) == 0) red[tid >> 6] = v;
    __syncthreads();
    return fmaxf(red[0], red[1]);
}
__device__ __forceinline__ float block_sum128(float v, float* red, int tid) {
    #pragma unroll
    for (int off = 32; off > 0; off >>= 1)
        v += __shfl_down(v, off, 64);
    __syncthreads();
    if ((tid & 63) == 0) red[tid >> 6] = v;
    __syncthreads();
    return red[0] + red[1];
}

// ---------- wave-per-dst bf16 aggregate: no LDS, no barriers, 4-deep pipeline ----------
__global__ void gat_aggregate_wave_kernel(const unsigned short* __restrict__ feat_bf,
                                          const float* __restrict__ el,
                                          const float* __restrict__ er,
                                          const int* __restrict__ offs,
                                          const int* __restrict__ counts,
                                          const int* __restrict__ perm,
                                          float* __restrict__ out, int Nd) {
    int wid  = threadIdx.x >> 6;           // wave in block: 0..3
    int lane = threadIdx.x & 63;
    int j = blockIdx.x * 4 + wid;
    if (j >= Nd) return;
    int cnt = counts[j];
    size_t orow = (size_t)j * D;
    if (cnt == 0) {
        ((float2*)(out + orow))[lane] = make_float2(0.0f, 0.0f);  // 64 x 8B = 512B
        return;
    }
    size_t beg = (size_t)(j >> BSHIFT) * PR + (size_t)offs[j];
    float erj = er[j];
    int sg = lane >> 4, u = lane & 15;
    const unsigned short* fb = feat_bf + (size_t)u * 8;
    float acc[8];
    #pragma unroll
    for (int k = 0; k < 8; ++k) acc[k] = 0.0f;

    if (cnt <= 64) {
        // one edge per lane, everything in registers
        int s = 0; float e = -INFINITY;
        if (lane < cnt) {
            s = perm[beg + lane];
            float t = el[s] + erj;
            e = (t >= 0.0f) ? t : 0.01f * t;   // leaky_relu
        }
        float m = e;
        #pragma unroll
        for (int off = 32; off > 0; off >>= 1)
            m = fmaxf(m, __shfl_xor(m, off, 64));
        float a = (lane < cnt) ? __expf(e - m) : 0.0f;
        float den = a;
        #pragma unroll
        for (int off = 32; off > 0; off >>= 1)
            den += __shfl_xor(den, off, 64);
        a *= (1.0f / den);                      // pre-normalized weight
        int nit = (cnt + 3) >> 2;               // uniform trip count for all lanes
        int it = 0;
        for (; it + 4 <= nit; it += 4) {        // 4-deep: four rows in flight
            int t0 = sg + (it << 2);            // t0 < cnt guaranteed (t0 <= 4*nit-13)
            int t1 = t0 + 4;
            int t2 = t0 + 8;
            int t3 = t0 + 12;
            int u1 = (t1 < cnt) ? t1 : 0;
            int u2 = (t2 < cnt) ? t2 : 0;
            int u3 = (t3 < cnt) ? t3 : 0;
            float w0 = __shfl(a, t0, 64); int s0 = __shfl(s, t0, 64);
            float w1 = __shfl(a, u1, 64); int s1 = __shfl(s, u1, 64);
            float w2 = __shfl(a, u2, 64); int s2 = __shfl(s, u2, 64);
            float w3 = __shfl(a, u3, 64); int s3 = __shfl(s, u3, 64);
            bool p1 = (t1 < cnt), p2 = (t2 < cnt), p3 = (t3 < cnt);
            uint4 v0 = *(const uint4*)(fb + (size_t)s0 * D);
            uint4 v1 = p1 ? *(const uint4*)(fb + (size_t)s1 * D) : make_uint4(0,0,0,0);
            uint4 v2 = p2 ? *(const uint4*)(fb + (size_t)s2 * D) : make_uint4(0,0,0,0);
            uint4 v3 = p3 ? *(const uint4*)(fb + (size_t)s3 * D) : make_uint4(0,0,0,0);
            float f[8];
            unpack2(v0.x, f[0], f[1]); unpack2(v0.y, f[2], f[3]);
            unpack2(v0.z, f[4], f[5]); unpack2(v0.w, f[6], f[7]);
            #pragma unroll
            for (int k = 0; k < 8; ++k) acc[k] += w0 * f[k];
            if (p1) {
                unpack2(v1.x, f[0], f[1]); unpack2(v1.y, f[2], f[3]);
                unpack2(v1.z, f[4], f[5]); unpack2(v1.w, f[6], f[7]);
                #pragma unroll
                for (int k = 0; k < 8; ++k) acc[k] += w1 * f[k];
            }
            if (p2) {
                unpack2(v2.x, f[0], f[1]); unpack2(v2.y, f[2], f[3]);
                unpack2(v2.z, f[4], f[5]); unpack2(v2.w, f[6], f[7]);
                #pragma unroll
                for (int k = 0; k < 8; ++k) acc[k] += w2 * f[k];
            }
            if (p3) {
                unpack2(v3.x, f[0], f[1]); unpack2(v3.y, f[2], f[3]);
                unpack2(v3.z, f[4], f[5]); unpack2(v3.w, f[6], f[7]);
                #pragma unroll
                for (int k = 0; k < 8; ++k) acc[k] += w3 * f[k];
            }
        }
        for (; it < nit; ++it) {                // tail (up to 3 single iterations)
            int t0 = sg + (it << 2);
            int u0 = (t0 < cnt) ? t0 : 0;
            float w0 = __shfl(a, u0, 64);
            int   s0 = __shfl(s, u0, 64);
            if (t0 < cnt) {
                uint4 v0 = *(const uint4*)(fb + (size_t)s0 * D);
                float f[8];
                unpack2(v0.x, f[0], f[1]); unpack2(v0.y, f[2], f[3]);
                unpack2(v0.z, f[4], f[5]); unpack2(v0.w, f[6], f[7]);
                #pragma unroll
                for (int k = 0; k < 8; ++k) acc[k] += w0 * f[k];
            }
        }
    } else {
        // chunked recompute path (cnt > 64)
        float lmax = -INFINITY;
        for (int t = lane; t < cnt; t += 64) {
            int s = perm[beg + t];
            float e = el[s] + erj;
            e = (e >= 0.0f) ? e : 0.01f * e;
            lmax = fmaxf(lmax, e);
        }
        float m = lmax;
        #pragma unroll
        for (int off = 32; off > 0; off >>= 1)
            m = fmaxf(m, __shfl_xor(m, off, 64));
        float lsum = 0.0f;
        for (int t = lane; t < cnt; t += 64) {
            int s = perm[beg + t];
            float e = el[s] + erj;
            e = (e >= 0.0f) ? e : 0.01f * e;
            lsum += __expf(e - m);
        }
        #pragma unroll
        for (int off = 32; off > 0; off >>= 1)
            lsum += __shfl_xor(lsum, off, 64);
        float inv = 1.0f / lsum;
        for (int bb = 0; bb < cnt; bb += 64) {
            int nn = min(64, cnt - bb);
            int s = 0; float a = 0.0f;
            if (lane < nn) {
                s = perm[beg + bb + lane];
                float e = el[s] + erj;
                e = (e >= 0.0f) ? e : 0.01f * e;
                a = __expf(e - m) * inv;
            }
            int nit = (nn + 3) >> 2;            // uniform trip count
            for (int it = 0; it < nit; ++it) {
                int t = sg + (it << 2);
                int tt = (t < nn) ? t : 0;
                float w = __shfl(a, tt, 64);
                int st  = __shfl(s, tt, 64);
                if (t < nn) {
                    uint4 v = *(const uint4*)(fb + (size_t)st * D);
                    float f[8];
                    unpack2(v.x, f[0], f[1]); unpack2(v.y, f[2], f[3]);
                    unpack2(v.z, f[4], f[5]); unpack2(v.w, f[6], f[7]);
                    #pragma unroll
                    for (int k = 0; k < 8; ++k) acc[k] += w * f[k];
                }
            }
        }
    }
    // reduce across the 4 subgroups (lane bits 4,5) — all 64 lanes active here
    #pragma unroll
    for (int k = 0; k < 8; ++k) {
        acc[k] += __shfl_xor(acc[k], 16, 64);
        acc[k] += __shfl_xor(acc[k], 32, 64);
    }
    if (sg == 0) {
        float* op = out + orow + (size_t)u * 8;
        ((float4*)op)[0] = make_float4(acc[0], acc[1], acc[2], acc[3]);
        ((float4*)op)[1] = make_float4(acc[4], acc[5], acc[6], acc[7]);
    }
}

// ================= fallback pipeline (only if workspace too small) =================
__global__ void hist_kernel(const int* __restrict__ dst, int E, int* __restrict__ counts) {
    int stride = gridDim.x * blockDim.x;
    for (int k = blockIdx.x * blockDim.x + threadIdx.x; k < E; k += stride)
        atomicAdd(&counts[dst[k]], 1);
}
__global__ void scan1_kernel(const int* __restrict__ counts, int* __restrict__ offsets,
                             int* __restrict__ blockSums, int N) {
    __shared__ int tile[256];
    int tid = threadIdx.x;
    int i = blockIdx.x * 256 + tid;
    int v = (i < N) ? counts[i] : 0;
    tile[tid] = v;
    __syncthreads();
    for (int off = 1; off < 256; off <<= 1) {
        int t = (tid >= off) ? tile[tid - off] : 0;
        __syncthreads();
        tile[tid] += t;
        __syncthreads();
    }
    int incl = tile[tid];
    if (i < N) offsets[i] = incl - v;
    if (tid == 255) blockSums[blockIdx.x] = incl;
}
__global__ void scan2_kernel(int* __restrict__ bs, int nb) {
    __shared__ int tile[256];
    int tid = threadIdx.x;
    int carry = 0;
    for (int base = 0; base < nb; base += 256) {
        int i = base + tid;
        int v = (i < nb) ? bs[i] : 0;
        __syncthreads();
        tile[tid] = v;
        __syncthreads();
        for (int off = 1; off < 256; off <<= 1) {
            int t = (tid >= off) ? tile[tid - off] : 0;
            __syncthreads();
            tile[tid] += t;
            __syncthreads();
        }
        int incl = tile[tid];
        if (i < nb) bs[i] = incl - v + carry;
        carry += tile[255];
    }
}
__global__ void fill_kernel(const int* __restrict__ src, const int* __restrict__ dst, int E,
                            const int* __restrict__ offsets, const int* __restrict__ bsum,
                            int* __restrict__ cursor, int* __restrict__ perm_src) {
    int stride = gridDim.x * blockDim.x;
    for (int k = blockIdx.x * blockDim.x + threadIdx.x; k < E; k += stride) {
        int j = dst[k];
        int p = offsets[j] + bsum[j >> BSHIFT] + atomicAdd(&cursor[j], 1);
        perm_src[p] = src[k];
    }
}
__global__ void gat_aggregate_f32_kernel(const float* __restrict__ feat_src,
                                         const float* __restrict__ el,
                                         const float* __restrict__ er,
                                         const int* __restrict__ offsets,
                                         const int* __restrict__ bsum,
                                         const int* __restrict__ counts,
                                         const int* __restrict__ perm_src,
                                         float* __restrict__ out, int Nd) {
    __shared__ float w_sh[CHUNK];
    __shared__ int   s_sh[CHUNK];
    __shared__ float red[2];
    int j = blockIdx.x;
    int tid = threadIdx.x;
    int cnt = counts[j];
    size_t orow = (size_t)j * D;
    if (cnt == 0) { out[orow + tid] = 0.0f; return; }
    int beg = offsets[j] + bsum[j >> BSHIFT];
    float erj = er[j];
    float acc = 0.0f;
    float inv;
    if (cnt <= CHUNK) {
        float lmax = -INFINITY;
        for (int t = tid; t < cnt; t += AGG_THREADS) {
            int s = perm_src[beg + t];
            float e = el[s] + erj;
            e = (e >= 0.0f) ? e : 0.01f * e;
            s_sh[t] = s; w_sh[t] = e;
            lmax = fmaxf(lmax, e);
        }
        float m = block_max128(lmax, red, tid);
        float lsum = 0.0f;
        for (int t = tid; t < cnt; t += AGG_THREADS) {
            float a = __expf(w_sh[t] - m);
            w_sh[t] = a; lsum += a;
        }
        float den = block_sum128(lsum, red, tid);
        inv = 1.0f / den;
        __syncthreads();
        for (int t = 0; t < cnt; ++t)
            acc += feat_src[(size_t)s_sh[t] * D + tid] * w_sh[t];
    } else {
        float lmax = -INFINITY;
        for (int t = tid; t < cnt; t += AGG_THREADS) {
            int s = perm_src[beg + t];
            float e = el[s] + erj;
            e = (e >= 0.0f) ? e : 0.01f * e;
            lmax = fmaxf(lmax, e);
        }
        float m = block_max128(lmax, red, tid);
        float lsum = 0.0f;
        for (int t = tid; t < cnt; t += AGG_THREADS) {
            int s = perm_src[beg + t];
            float e = el[s] + erj;
            e = (e >= 0.0f) ? e : 0.01f * e;
            lsum += __expf(e - m);
        }
        float den = block_sum128(lsum, red, tid);
        inv = 1.0f / den;
        for (int bb = 0; bb < cnt; bb += CHUNK) {
            int n = min(CHUNK, cnt - bb);
            __syncthreads();
            for (int t = tid; t < n; t += AGG_THREADS) {
                int s = perm_src[beg + bb + t];
                float e = el[s] + erj;
                e = (e >= 0.0f) ? e : 0.01f * e;
                s_sh[t] = s;
                w_sh[t] = __expf(e - m);
            }
            __syncthreads();
            for (int t = 0; t < n; ++t)
                acc += feat_src[(size_t)s_sh[t] * D + tid] * w_sh[t];
        }
    }
    out[orow + tid] = acc * inv;
}

extern "C" void kernel_launch(void* const* d_in, const int* in_sizes, int n_in,
                              void* d_out, int out_size, void* d_ws, size_t ws_size,
                              hipStream_t stream) {
    const float* feat_src = (const float*)d_in[0];
    const float* feat_dst = (const float*)d_in[1];
    const int*   src      = (const int*)d_in[2];
    const int*   dst      = (const int*)d_in[3];
    const float* attn_l   = (const float*)d_in[4];
    const float* attn_r   = (const float*)d_in[5];
    float* out = (float*)d_out;

    int Ns = in_sizes[0] / D;
    int Nd = in_sizes[1] / D;
    int E  = in_sizes[2];
    int NBK = (Nd + (1 << BSHIFT) - 1) >> BSHIFT;
    int NWG = (E + PCHUNK - 1) / PCHUNK;

    char* p = (char*)d_ws;
    auto carve = [&](size_t bytes) { void* r = (void*)p; p += (bytes + 255) & ~(size_t)255; return r; };
    float* el      = (float*)carve((size_t)Ns * 4);
    float* er      = (float*)carve((size_t)Nd * 4);
    int*   counts  = (int*)carve((size_t)Nd * 4);
    int*   offs    = (int*)carve((size_t)Nd * 4);       // fallback: 'offsets'
    int*   gcursor = (int*)carve((size_t)Nd * 4);       // fallback only
    int*   bsums   = (int*)carve((size_t)NBK * 4);      // fallback only
    int*   cnt_tab = (int*)carve((size_t)NWG * NBK * 4);
    int*   loc_tab = (int*)carve((size_t)NWG * NBK * 4);
    int*   perm    = (int*)carve((size_t)NBK * PR * 4); // >= E*4, shared w/ fallback
    uint2* bins    = (uint2*)carve((size_t)NWG * PCHUNK * 8);
    size_t used    = (size_t)(p - (char*)d_ws);
    size_t bf_bytes = (size_t)Ns * D * 2;
    unsigned short* feat_bf = (unsigned short*)carve(bf_bytes);

    int fast = (NBK <= MAXB && NWG <= MAXWG &&
                used + bf_bytes + 256 <= ws_size) ? 1 : 0;

    int total = Ns + Nd;
    int prep_blocks = (total + 7) / 8;
    if (fast) {
        // fused prep+partition: partition blocks first (issue early), prep after
        prep_partition_kernel<<<NWG + prep_blocks, 256, 0, stream>>>(
            feat_src, feat_dst, attn_l, attn_r, el, er, feat_bf, Ns, Nd,
            src, dst, E, NBK, NWG, bins, cnt_tab, loc_tab);
        bucket_kernel<<<NBK, 512, 0, stream>>>(bins, cnt_tab, loc_tab, NBK, NWG,
                                               counts, offs, perm, Nd);
        gat_aggregate_wave_kernel<<<(Nd + 3) / 4, 256, 0, stream>>>(feat_bf, el, er, offs,
                                                                    counts, perm, out, Nd);
    } else {
        hipMemsetAsync(counts, 0, (size_t)Nd * 4, stream);
        hipMemsetAsync(gcursor, 0, (size_t)Nd * 4, stream);
        prep_kernel<<<prep_blocks, 256, 0, stream>>>(feat_src, feat_dst, attn_l, attn_r,
                                                     el, er, nullptr, 0, Ns, Nd);
        hist_kernel<<<2048, 256, 0, stream>>>(dst, E, counts);
        scan1_kernel<<<NBK, 256, 0, stream>>>(counts, offs, bsums, Nd);
        scan2_kernel<<<1, 256, 0, stream>>>(bsums, NBK);
        fill_kernel<<<2048, 256, 0, stream>>>(src, dst, E, offs, bsums, gcursor, perm);
        gat_aggregate_f32_kernel<<<Nd, AGG_THREADS, 0, stream>>>(feat_src, el, er, offs,
                                                                 bsums, counts, perm, out, Nd);
    }
}

// Round 16
// 240.532 us; speedup vs baseline: 1.1504x; 1.0128x over previous
//
#include <hip/hip_runtime.h>
#include <hip/hip_bf16.h>
#include <math.h>

#define D 128
#define AGG_THREADS 128
#define CHUNK 512
#define BSHIFT 8                 // 256 dst nodes per bucket (R2/R12-verified best)
#define MAXB 512                 // max buckets (nbk=391 at Nd=100K)
#define MAXWG 1024               // max partition WGs (LDS arrays in bucket kernel)
#define PCHUNK 2048              // edges per partition WG (R13-verified)
#define PE 8                     // PCHUNK / 256
#define EBUF_CAP 5120            // LDS staging cap in bucket kernel (mean 4096, 16 sigma)
#define PR 8192                  // perm region stride per bucket (45 sigma)

// ---------- helpers ----------
__device__ __forceinline__ unsigned short f2bf(float f) {
    union { float f; unsigned int u; } c; c.f = f;
    unsigned int u = c.u;
    unsigned int r = (u + 0x7FFFu + ((u >> 16) & 1u)) >> 16;  // RNE
    return (unsigned short)r;
}
__device__ __forceinline__ void unpack2(unsigned int w, float& lo, float& hi) {
    union { unsigned int u; float f; } c;
    c.u = w << 16;          lo = c.f;
    c.u = w & 0xFFFF0000u;  hi = c.f;
}

// 8-wave parallel exclusive scan over arr[0..n) in LDS -> outp[0..n).
// Call with 512 threads; barriers inside; returns grand total.
__device__ __forceinline__ int scan8w(const int* __restrict__ arr, int* __restrict__ outp,
                                      int n, int tid, int* wsum8) {
    int wv = tid >> 6, lane = tid & 63;
    int nchunk = (n + 63) >> 6;
    int cpw = (nchunk + 7) >> 3;
    int c0 = wv * cpw, c1 = min(nchunk, c0 + cpw);
    int carry = 0;
    for (int c = c0; c < c1; ++c) {
        int i = (c << 6) + lane;
        int v = (i < n) ? arr[i] : 0;
        int x = v;
        #pragma unroll
        for (int off = 1; off < 64; off <<= 1) {
            int t = __shfl_up(x, off, 64);
            if (lane >= off) x += t;
        }
        if (i < n) outp[i] = x - v + carry;
        carry += __shfl(x, 63, 64);
    }
    if (lane == 0) wsum8[wv] = carry;
    __syncthreads();
    int wbase = 0;
    for (int u = 0; u < wv; ++u) wbase += wsum8[u];
    if (wbase) {
        for (int c = c0; c < c1; ++c) {
            int i = (c << 6) + lane;
            if (i < n) outp[i] += wbase;
        }
    }
    int tot = 0;
    #pragma unroll
    for (int u = 0; u < 8; ++u) tot += wsum8[u];
    __syncthreads();
    return tot;
}

// ---------- FUSED prep + partition: heterogeneous block roles (R13-verified) ----------
__global__ void prep_partition_kernel(const float* __restrict__ feat_src,
                                      const float* __restrict__ feat_dst,
                                      const float* __restrict__ attn_l,
                                      const float* __restrict__ attn_r,
                                      float* __restrict__ el, float* __restrict__ er,
                                      unsigned short* __restrict__ feat_bf,
                                      int Ns, int Nd,
                                      const int* __restrict__ src,
                                      const int* __restrict__ dst,
                                      int E, int nbk, int nwg,
                                      uint2* __restrict__ bins,
                                      int* __restrict__ cnt_tab,
                                      int* __restrict__ loc_tab) {
    __shared__ int hist[MAXB];
    __shared__ int lstart[MAXB];
    __shared__ int cursor[MAXB];
    __shared__ uint2 sbuf[PCHUNK];         // 16 KB; total LDS ~22 KB
    int tid = threadIdx.x;

    if ((int)blockIdx.x < nwg) {
        // ---------------- partition role ----------------
        int w = blockIdx.x;
        int e0 = w * PCHUNK;
        int e1 = min(E, e0 + PCHUNK);
        int n = e1 - e0;

        for (int i = tid; i < nbk; i += 256) hist[i] = 0;
        __syncthreads();

        int es[PE], ed[PE];
        #pragma unroll
        for (int k = 0; k < PE; ++k) {
            int idx = e0 + k * 256 + tid;
            if (idx < e1) {
                es[k] = src[idx];
                ed[k] = dst[idx];
                atomicAdd(&hist[ed[k] >> BSHIFT], 1);
            }
        }
        __syncthreads();

        // exclusive scan of hist[0..nbk) by wave 0, 64-wide chunks (nbk<=512: <=8)
        if (tid < 64) {
            int carry = 0;
            for (int c = 0; c < nbk; c += 64) {
                int i = c + tid;
                int v = (i < nbk) ? hist[i] : 0;
                int x = v;
                #pragma unroll
                for (int off = 1; off < 64; off <<= 1) {
                    int t = __shfl_up(x, off, 64);
                    if (tid >= off) x += t;
                }
                if (i < nbk) lstart[i] = x - v + carry;
                carry += __shfl(x, 63, 64);
            }
        }
        __syncthreads();

        for (int i = tid; i < nbk; i += 256) {
            cnt_tab[(size_t)w * nbk + i] = hist[i];
            loc_tab[(size_t)w * nbk + i] = lstart[i];
            cursor[i] = 0;
        }
        __syncthreads();

        #pragma unroll
        for (int k = 0; k < PE; ++k) {
            int idx = e0 + k * 256 + tid;
            if (idx < e1) {
                int b = ed[k] >> BSHIFT;
                int r = lstart[b] + atomicAdd(&cursor[b], 1);
                sbuf[r] = make_uint2((unsigned)es[k], (unsigned)ed[k]);
            }
        }
        __syncthreads();

        uint2* obase = bins + (size_t)w * PCHUNK;
        for (int t = tid; t < n; t += 256) obase[t] = sbuf[t];   // coalesced
    } else {
        // ---------------- prep role ----------------
        int half = tid >> 5;               // 0..7 (8 rows per 256-thread block)
        int lane = tid & 31;
        int node = ((int)blockIdx.x - nwg) * 8 + half;
        if (node >= Ns + Nd) return;
        bool is_src = node < Ns;
        const float* feat = is_src ? feat_src + (size_t)node * D
                                   : feat_dst + (size_t)(node - Ns) * D;
        const float* attn = is_src ? attn_l : attn_r;
        float4 a = ((const float4*)attn)[lane];
        float4 v = ((const float4*)feat)[lane];
        if (is_src) {
            ushort4 h; h.x = f2bf(v.x); h.y = f2bf(v.y); h.z = f2bf(v.z); h.w = f2bf(v.w);
            ((ushort4*)(feat_bf + (size_t)node * D))[lane] = h;
        }
        float s = v.x * a.x + v.y * a.y + v.z * a.z + v.w * a.w;
        #pragma unroll
        for (int off = 16; off > 0; off >>= 1)
            s += __shfl_xor(s, off, 64);   // xor<=16 stays within each 32-lane half
        if (lane == 0) {
            if (is_src) el[node] = s;
            else        er[node - Ns] = s;
        }
    }
}

// ---------- standalone prep (fallback path only) ----------
__global__ void prep_kernel(const float* __restrict__ feat_src,
                            const float* __restrict__ feat_dst,
                            const float* __restrict__ attn_l,
                            const float* __restrict__ attn_r,
                            float* __restrict__ el, float* __restrict__ er,
                            unsigned short* __restrict__ feat_bf, int store_bf,
                            int Ns, int Nd) {
    int half = threadIdx.x >> 5;
    int lane = threadIdx.x & 31;
    int node = blockIdx.x * 8 + half;
    if (node >= Ns + Nd) return;
    bool is_src = node < Ns;
    const float* feat = is_src ? feat_src + (size_t)node * D
                               : feat_dst + (size_t)(node - Ns) * D;
    const float* attn = is_src ? attn_l : attn_r;
    float4 a = ((const float4*)attn)[lane];
    float4 v = ((const float4*)feat)[lane];
    if (is_src && store_bf) {
        ushort4 h; h.x = f2bf(v.x); h.y = f2bf(v.y); h.z = f2bf(v.z); h.w = f2bf(v.w);
        ((ushort4*)(feat_bf + (size_t)node * D))[lane] = h;
    }
    float s = v.x * a.x + v.y * a.y + v.z * a.z + v.w * a.w;
    #pragma unroll
    for (int off = 16; off > 0; off >>= 1)
        s += __shfl_xor(s, off, 64);
    if (lane == 0) {
        if (is_src) el[node] = s;
        else        er[node - Ns] = s;
    }
}

// ---------- bucket kernel: 512 threads, direct per-segment copy (R15-verified) ----------
__global__ void bucket_kernel(const uint2* __restrict__ bins,
                              const int* __restrict__ cnt_tab, const int* __restrict__ loc_tab,
                              int nbk, int nwg,
                              int* __restrict__ counts, int* __restrict__ offs,
                              int* __restrict__ perm, int Nd) {
    __shared__ uint2 ebuf[EBUF_CAP];       // 40 KB
    __shared__ int wcnt[MAXWG];
    __shared__ int wdst[MAXWG];
    __shared__ int sbase[MAXWG];
    __shared__ int cnt256[256];
    __shared__ int off256[256];
    __shared__ int cur256[256];
    __shared__ int wsum8[8];

    int b = blockIdx.x, tid = threadIdx.x;
    int base = b << BSHIFT;

    for (int i = tid; i < nwg; i += 512) wcnt[i] = cnt_tab[(size_t)i * nbk + b];
    if (tid < 256) { cnt256[tid] = 0; cur256[tid] = 0; }
    __syncthreads();

    // 8-wave exclusive scan over nwg segment counts
    int n = scan8w(wcnt, wdst, nwg, tid, wsum8);
    bool fits = (n <= EBUF_CAP);

    for (int w = tid; w < nwg; w += 512)
        sbase[w] = w * PCHUNK + loc_tab[(size_t)w * nbk + b] - wdst[w];
    __syncthreads();

    if (fits) {
        // direct per-segment gather into LDS at the scanned offset; count fused
        for (int w = tid; w < nwg; w += 512) {
            int c = wcnt[w];
            if (c) {
                const uint2* sp = bins + (size_t)(sbase[w] + wdst[w]);
                int d0 = wdst[w];
                for (int k = 0; k < c; ++k) {
                    uint2 e = sp[k];
                    ebuf[d0 + k] = e;
                    atomicAdd(&cnt256[(int)e.y - base], 1);
                }
            }
        }
    } else {
        // slow path (statistically unreachable): count straight from global
        for (int w = tid; w < nwg; w += 512) {
            int c = wcnt[w];
            const uint2* sp = bins + (size_t)(sbase[w] + wdst[w]);
            for (int k = 0; k < c; ++k)
                atomicAdd(&cnt256[(int)sp[k].y - base], 1);
        }
    }
    __syncthreads();

    // wave-parallel exclusive scan of the 256 per-dst counts (2 barriers)
    scan8w(cnt256, off256, 256, tid, wsum8);
    if (tid < 256) {
        int v = cnt256[tid];
        int myoff = off256[tid];
        int i = base + tid;
        if (i < Nd) {
            int c = v;
            if (myoff + c > PR) c = max(0, PR - myoff);   // paranoia clamp
            counts[i] = c;
            offs[i]   = myoff;
        }
    }
    __syncthreads();

    // rank + write perm into this bucket's fixed region
    size_t rbase = (size_t)b * PR;
    if (fits) {
        for (int t = tid; t < n; t += 512) {
            uint2 e = ebuf[t];
            int d = (int)e.y - base;
            int r = atomicAdd(&cur256[d], 1);
            int slot = off256[d] + r;
            if (slot < PR) perm[rbase + slot] = (int)e.x;
        }
    } else {
        for (int w = tid; w < nwg; w += 512) {
            int c = wcnt[w];
            const uint2* sp = bins + (size_t)(sbase[w] + wdst[w]);
            for (int k = 0; k < c; ++k) {
                uint2 e = sp[k];
                int d = (int)e.y - base;
                int r = atomicAdd(&cur256[d], 1);
                int slot = off256[d] + r;
                if (slot < PR) perm[rbase + slot] = (int)e.x;
            }
        }
    }
}

// ---------- block reductions (128 threads = 2 waves) for fallback aggregate ----------
__device__ __forceinline__ float block_max128(float v, float* red, int tid) {
    #pragma unroll
    for (int off = 32; off > 0; off >>= 1)
        v = fmaxf(v, __shfl_down(v, off, 64));
    __syncthreads();
    if ((tid & 63) == 0) red[tid >> 6] = v;
    __syncthreads();
    return fmaxf(red[0], red[1]);
}
__device__ __forceinline__ float block_sum128(float v, float* red, int tid) {
    #pragma unroll
    for (int off = 32; off > 0; off >>= 1)
        v += __shfl_down(v, off, 64);
    __syncthreads();
    if ((tid & 63) == 0) red[tid >> 6] = v;
    __syncthreads();
    return red[0] + red[1];
}

// ---------- aggregate: HALF-WAVE per dst (cnt<=32 fast path) ----------
// 256-thread block = 4 waves x 2 half-waves = 8 dst per block.
// Fast path (wave-uniform: wave-max cnt <= 32): each 32-lane half owns one dst;
// softmax machinery amortized over 2 dst/wave; all __shfl sources clamped
// inside the owning half with uniform trip counts (wave64-safe).
// Slow path: the wave processes its 2 dst sequentially with the R15-verified
// full-wave code (cnt<=64 register path + chunked recompute path).
__global__ void gat_aggregate_wave_kernel(const unsigned short* __restrict__ feat_bf,
                                          const float* __restrict__ el,
                                          const float* __restrict__ er,
                                          const int* __restrict__ offs,
                                          const int* __restrict__ counts,
                                          const int* __restrict__ perm,
                                          float* __restrict__ out, int Nd) {
    int wid  = threadIdx.x >> 6;           // wave in block: 0..3
    int lane = threadIdx.x & 63;
    int jbase = blockIdx.x * 8 + wid * 2;
    if (jbase >= Nd) return;               // wave-uniform

    int halfid = lane >> 5;                // 0,1
    int hl = lane & 31;                    // lane within half
    int j = jbase + halfid;
    bool jv = (j < Nd);
    int cnt = jv ? counts[j] : 0;

    // wave-uniform max of cnt
    int mc = cnt;
    #pragma unroll
    for (int off = 32; off > 0; off >>= 1)
        mc = max(mc, __shfl_xor(mc, off, 64));

    if (mc <= 32) {
        // ---------- half-wave fast path ----------
        size_t beg = jv ? ((size_t)(j >> BSHIFT) * PR + (size_t)offs[j]) : 0;
        float erj = jv ? er[j] : 0.0f;
        int s = 0; float e = -INFINITY;
        if (hl < cnt) {
            s = perm[beg + hl];
            float t = el[s] + erj;
            e = (t >= 0.0f) ? t : 0.01f * t;   // leaky_relu
        }
        float m = e;
        #pragma unroll
        for (int off = 16; off > 0; off >>= 1)
            m = fmaxf(m, __shfl_xor(m, off, 64));   // stays within each half
        float a = (hl < cnt) ? __expf(e - m) : 0.0f;
        float den = a;
        #pragma unroll
        for (int off = 16; off > 0; off >>= 1)
            den += __shfl_xor(den, off, 64);
        a *= (den > 0.0f) ? (1.0f / den) : 0.0f;    // pre-normalized weight

        int sg2 = hl >> 4, u = hl & 15;             // 2 subgroups of 16 per half
        const unsigned short* fb = feat_bf + (size_t)u * 8;
        int hbase = halfid << 5;
        float acc[8];
        #pragma unroll
        for (int k = 0; k < 8; ++k) acc[k] = 0.0f;

        int nit = (mc + 1) >> 1;            // wave-uniform trips (row step 2)
        int it = 0;
        for (; it + 2 <= nit; it += 2) {    // 2-deep: two rows in flight per half
            int t0 = sg2 + (it << 1);
            int t1 = t0 + 2;
            int u0 = (t0 < cnt) ? t0 : 0;
            int u1 = (t1 < cnt) ? t1 : 0;
            float w0 = __shfl(a, hbase + u0, 64); int s0 = __shfl(s, hbase + u0, 64);
            float w1 = __shfl(a, hbase + u1, 64); int s1 = __shfl(s, hbase + u1, 64);
            bool p0 = (t0 < cnt), p1 = (t1 < cnt);
            uint4 v0 = p0 ? *(const uint4*)(fb + (size_t)s0 * D) : make_uint4(0,0,0,0);
            uint4 v1 = p1 ? *(const uint4*)(fb + (size_t)s1 * D) : make_uint4(0,0,0,0);
            float f[8];
            if (p0) {
                unpack2(v0.x, f[0], f[1]); unpack2(v0.y, f[2], f[3]);
                unpack2(v0.z, f[4], f[5]); unpack2(v0.w, f[6], f[7]);
                #pragma unroll
                for (int k = 0; k < 8; ++k) acc[k] += w0 * f[k];
            }
            if (p1) {
                unpack2(v1.x, f[0], f[1]); unpack2(v1.y, f[2], f[3]);
                unpack2(v1.z, f[4], f[5]); unpack2(v1.w, f[6], f[7]);
                #pragma unroll
                for (int k = 0; k < 8; ++k) acc[k] += w1 * f[k];
            }
        }
        if (it < nit) {                     // tail
            int t0 = sg2 + (it << 1);
            int u0 = (t0 < cnt) ? t0 : 0;
            float w0 = __shfl(a, hbase + u0, 64);
            int   s0 = __shfl(s, hbase + u0, 64);
            if (t0 < cnt) {
                uint4 v0 = *(const uint4*)(fb + (size_t)s0 * D);
                float f[8];
                unpack2(v0.x, f[0], f[1]); unpack2(v0.y, f[2], f[3]);
                unpack2(v0.z, f[4], f[5]); unpack2(v0.w, f[6], f[7]);
                #pragma unroll
                for (int k = 0; k < 8; ++k) acc[k] += w0 * f[k];
            }
        }
        // reduce across the 2 subgroups within each half
        #pragma unroll
        for (int k = 0; k < 8; ++k)
            acc[k] += __shfl_xor(acc[k], 16, 64);
        if (sg2 == 0 && jv) {
            float* op = out + (size_t)j * D + (size_t)u * 8;
            ((float4*)op)[0] = make_float4(acc[0], acc[1], acc[2], acc[3]);
            ((float4*)op)[1] = make_float4(acc[4], acc[5], acc[6], acc[7]);
        }
        return;
    }

    // ---------- slow path: full wave per dst, 2 dst sequentially ----------
    int sg = lane >> 4, u = lane & 15;
    const unsigned short* fb = feat_bf + (size_t)u * 8;
    for (int q = 0; q < 2; ++q) {
        int jj = jbase + q;
        if (jj >= Nd) break;
        int cq = counts[jj];
        size_t orow = (size_t)jj * D;
        if (cq == 0) {
            ((float2*)(out + orow))[lane] = make_float2(0.0f, 0.0f);
            continue;
        }
        size_t beg = (size_t)(jj >> BSHIFT) * PR + (size_t)offs[jj];
        float erj = er[jj];
        float acc[8];
        #pragma unroll
        for (int k = 0; k < 8; ++k) acc[k] = 0.0f;

        if (cq <= 64) {
            int s = 0; float e = -INFINITY;
            if (lane < cq) {
                s = perm[beg + lane];
                float t = el[s] + erj;
                e = (t >= 0.0f) ? t : 0.01f * t;
            }
            float m = e;
            #pragma unroll
            for (int off = 32; off > 0; off >>= 1)
                m = fmaxf(m, __shfl_xor(m, off, 64));
            float a = (lane < cq) ? __expf(e - m) : 0.0f;
            float den = a;
            #pragma unroll
            for (int off = 32; off > 0; off >>= 1)
                den += __shfl_xor(den, off, 64);
            a *= (1.0f / den);
            int nit = (cq + 3) >> 2;
            for (int it = 0; it < nit; ++it) {
                int t = sg + (it << 2);
                int tt = (t < cq) ? t : 0;
                float w = __shfl(a, tt, 64);
                int st  = __shfl(s, tt, 64);
                if (t < cq) {
                    uint4 v = *(const uint4*)(fb + (size_t)st * D);
                    float f[8];
                    unpack2(v.x, f[0], f[1]); unpack2(v.y, f[2], f[3]);
                    unpack2(v.z, f[4], f[5]); unpack2(v.w, f[6], f[7]);
                    #pragma unroll
                    for (int k = 0; k < 8; ++k) acc[k] += w * f[k];
                }
            }
        } else {
            float lmax = -INFINITY;
            for (int t = lane; t < cq; t += 64) {
                int s = perm[beg + t];
                float e = el[s] + erj;
                e = (e >= 0.0f) ? e : 0.01f * e;
                lmax = fmaxf(lmax, e);
            }
            float m = lmax;
            #pragma unroll
            for (int off = 32; off > 0; off >>= 1)
                m = fmaxf(m, __shfl_xor(m, off, 64));
            float lsum = 0.0f;
            for (int t = lane; t < cq; t += 64) {
                int s = perm[beg + t];
                float e = el[s] + erj;
                e = (e >= 0.0f) ? e : 0.01f * e;
                lsum += __expf(e - m);
            }
            #pragma unroll
            for (int off = 32; off > 0; off >>= 1)
                lsum += __shfl_xor(lsum, off, 64);
            float inv = 1.0f / lsum;
            for (int bb = 0; bb < cq; bb += 64) {
                int nn = min(64, cq - bb);
                int s = 0; float a = 0.0f;
                if (lane < nn) {
                    s = perm[beg + bb + lane];
                    float e = el[s] + erj;
                    e = (e >= 0.0f) ? e : 0.01f * e;
                    a = __expf(e - m) * inv;
                }
                int nit = (nn + 3) >> 2;
                for (int it = 0; it < nit; ++it) {
                    int t = sg + (it << 2);
                    int tt = (t < nn) ? t : 0;
                    float w = __shfl(a, tt, 64);
                    int st  = __shfl(s, tt, 64);
                    if (t < nn) {
                        uint4 v = *(const uint4*)(fb + (size_t)st * D);
                        float f[8];
                        unpack2(v.x, f[0], f[1]); unpack2(v.y, f[2], f[3]);
                        unpack2(v.z, f[4], f[5]); unpack2(v.w, f[6], f[7]);
                        #pragma unroll
                        for (int k = 0; k < 8; ++k) acc[k] += w * f[k];
                    }
                }
            }
        }
        #pragma unroll
        for (int k = 0; k < 8; ++k) {
            acc[k] += __shfl_xor(acc[k], 16, 64);
            acc[k] += __shfl_xor(acc[k], 32, 64);
        }
        if (sg == 0) {
            float* op = out + orow + (size_t)u * 8;
            ((float4*)op)[0] = make_float4(acc[0], acc[1], acc[2], acc[3]);
            ((float4*)op)[1] = make_float4(acc[4], acc[5], acc[6], acc[7]);
        }
    }
}

// ================= fallback pipeline (only if workspace too small) =================
__global__ void hist_kernel(const int* __restrict__ dst, int E, int* __restrict__ counts) {
    int stride = gridDim.x * blockDim.x;
    for (int k = blockIdx.x * blockDim.x + threadIdx.x; k < E; k += stride)
        atomicAdd(&counts[dst[k]], 1);
}
__global__ void scan1_kernel(const int* __restrict__ counts, int* __restrict__ offsets,
                             int* __restrict__ blockSums, int N) {
    __shared__ int tile[256];
    int tid = threadIdx.x;
    int i = blockIdx.x * 256 + tid;
    int v = (i < N) ? counts[i] : 0;
    tile[tid] = v;
    __syncthreads();
    for (int off = 1; off < 256; off <<= 1) {
        int t = (tid >= off) ? tile[tid - off] : 0;
        __syncthreads();
        tile[tid] += t;
        __syncthreads();
    }
    int incl = tile[tid];
    if (i < N) offsets[i] = incl - v;
    if (tid == 255) blockSums[blockIdx.x] = incl;
}
__global__ void scan2_kernel(int* __restrict__ bs, int nb) {
    __shared__ int tile[256];
    int tid = threadIdx.x;
    int carry = 0;
    for (int base = 0; base < nb; base += 256) {
        int i = base + tid;
        int v = (i < nb) ? bs[i] : 0;
        __syncthreads();
        tile[tid] = v;
        __syncthreads();
        for (int off = 1; off < 256; off <<= 1) {
            int t = (tid >= off) ? tile[tid - off] : 0;
            __syncthreads();
            tile[tid] += t;
            __syncthreads();
        }
        int incl = tile[tid];
        if (i < nb) bs[i] = incl - v + carry;
        carry += tile[255];
    }
}
__global__ void fill_kernel(const int* __restrict__ src, const int* __restrict__ dst, int E,
                            const int* __restrict__ offsets, const int* __restrict__ bsum,
                            int* __restrict__ cursor, int* __restrict__ perm_src) {
    int stride = gridDim.x * blockDim.x;
    for (int k = blockIdx.x * blockDim.x + threadIdx.x; k < E; k += stride) {
        int j = dst[k];
        int p = offsets[j] + bsum[j >> BSHIFT] + atomicAdd(&cursor[j], 1);
        perm_src[p] = src[k];
    }
}
__global__ void gat_aggregate_f32_kernel(const float* __restrict__ feat_src,
                                         const float* __restrict__ el,
                                         const float* __restrict__ er,
                                         const int* __restrict__ offsets,
                                         const int* __restrict__ bsum,
                                         const int* __restrict__ counts,
                                         const int* __restrict__ perm_src,
                                         float* __restrict__ out, int Nd) {
    __shared__ float w_sh[CHUNK];
    __shared__ int   s_sh[CHUNK];
    __shared__ float red[2];
    int j = blockIdx.x;
    int tid = threadIdx.x;
    int cnt = counts[j];
    size_t orow = (size_t)j * D;
    if (cnt == 0) { out[orow + tid] = 0.0f; return; }
    int beg = offsets[j] + bsum[j >> BSHIFT];
    float erj = er[j];
    float acc = 0.0f;
    float inv;
    if (cnt <= CHUNK) {
        float lmax = -INFINITY;
        for (int t = tid; t < cnt; t += AGG_THREADS) {
            int s = perm_src[beg + t];
            float e = el[s] + erj;
            e = (e >= 0.0f) ? e : 0.01f * e;
            s_sh[t] = s; w_sh[t] = e;
            lmax = fmaxf(lmax, e);
        }
        float m = block_max128(lmax, red, tid);
        float lsum = 0.0f;
        for (int t = tid; t < cnt; t += AGG_THREADS) {
            float a = __expf(w_sh[t] - m);
            w_sh[t] = a; lsum += a;
        }
        float den = block_sum128(lsum, red, tid);
        inv = 1.0f / den;
        __syncthreads();
        for (int t = 0; t < cnt; ++t)
            acc += feat_src[(size_t)s_sh[t] * D + tid] * w_sh[t];
    } else {
        float lmax = -INFINITY;
        for (int t = tid; t < cnt; t += AGG_THREADS) {
            int s = perm_src[beg + t];
            float e = el[s] + erj;
            e = (e >= 0.0f) ? e : 0.01f * e;
            lmax = fmaxf(lmax, e);
        }
        float m = block_max128(lmax, red, tid);
        float lsum = 0.0f;
        for (int t = tid; t < cnt; t += AGG_THREADS) {
            int s = perm_src[beg + t];
            float e = el[s] + erj;
            e = (e >= 0.0f) ? e : 0.01f * e;
            lsum += __expf(e - m);
        }
        float den = block_sum128(lsum, red, tid);
        inv = 1.0f / den;
        for (int bb = 0; bb < cnt; bb += CHUNK) {
            int n = min(CHUNK, cnt - bb);
            __syncthreads();
            for (int t = tid; t < n; t += AGG_THREADS) {
                int s = perm_src[beg + bb + t];
                float e = el[s] + erj;
                e = (e >= 0.0f) ? e : 0.01f * e;
                s_sh[t] = s;
                w_sh[t] = __expf(e - m);
            }
            __syncthreads();
            for (int t = 0; t < n; ++t)
                acc += feat_src[(size_t)s_sh[t] * D + tid] * w_sh[t];
        }
    }
    out[orow + tid] = acc * inv;
}

extern "C" void kernel_launch(void* const* d_in, const int* in_sizes, int n_in,
                              void* d_out, int out_size, void* d_ws, size_t ws_size,
                              hipStream_t stream) {
    const float* feat_src = (const float*)d_in[0];
    const float* feat_dst = (const float*)d_in[1];
    const int*   src      = (const int*)d_in[2];
    const int*   dst      = (const int*)d_in[3];
    const float* attn_l   = (const float*)d_in[4];
    const float* attn_r   = (const float*)d_in[5];
    float* out = (float*)d_out;

    int Ns = in_sizes[0] / D;
    int Nd = in_sizes[1] / D;
    int E  = in_sizes[2];
    int NBK = (Nd + (1 << BSHIFT) - 1) >> BSHIFT;
    int NWG = (E + PCHUNK - 1) / PCHUNK;

    char* p = (char*)d_ws;
    auto carve = [&](size_t bytes) { void* r = (void*)p; p += (bytes + 255) & ~(size_t)255; return r; };
    float* el      = (float*)carve((size_t)Ns * 4);
    float* er      = (float*)carve((size_t)Nd * 4);
    int*   counts  = (int*)carve((size_t)Nd * 4);
    int*   offs    = (int*)carve((size_t)Nd * 4);       // fallback: 'offsets'
    int*   gcursor = (int*)carve((size_t)Nd * 4);       // fallback only
    int*   bsums   = (int*)carve((size_t)NBK * 4);      // fallback only
    int*   cnt_tab = (int*)carve((size_t)NWG * NBK * 4);
    int*   loc_tab = (int*)carve((size_t)NWG * NBK * 4);
    int*   perm    = (int*)carve((size_t)NBK * PR * 4); // >= E*4, shared w/ fallback
    uint2* bins    = (uint2*)carve((size_t)NWG * PCHUNK * 8);
    size_t used    = (size_t)(p - (char*)d_ws);
    size_t bf_bytes = (size_t)Ns * D * 2;
    unsigned short* feat_bf = (unsigned short*)carve(bf_bytes);

    int fast = (NBK <= MAXB && NWG <= MAXWG &&
                used + bf_bytes + 256 <= ws_size) ? 1 : 0;

    int total = Ns + Nd;
    int prep_blocks = (total + 7) / 8;
    if (fast) {
        // fused prep+partition: partition blocks first (issue early), prep after
        prep_partition_kernel<<<NWG + prep_blocks, 256, 0, stream>>>(
            feat_src, feat_dst, attn_l, attn_r, el, er, feat_bf, Ns, Nd,
            src, dst, E, NBK, NWG, bins, cnt_tab, loc_tab);
        bucket_kernel<<<NBK, 512, 0, stream>>>(bins, cnt_tab, loc_tab, NBK, NWG,
                                               counts, offs, perm, Nd);
        gat_aggregate_wave_kernel<<<(Nd + 7) / 8, 256, 0, stream>>>(feat_bf, el, er, offs,
                                                                    counts, perm, out, Nd);
    } else {
        hipMemsetAsync(counts, 0, (size_t)Nd * 4, stream);
        hipMemsetAsync(gcursor, 0, (size_t)Nd * 4, stream);
        prep_kernel<<<prep_blocks, 256, 0, stream>>>(feat_src, feat_dst, attn_l, attn_r,
                                                     el, er, nullptr, 0, Ns, Nd);
        hist_kernel<<<2048, 256, 0, stream>>>(dst, E, counts);
        scan1_kernel<<<NBK, 256, 0, stream>>>(counts, offs, bsums, Nd);
        scan2_kernel<<<1, 256, 0, stream>>>(bsums, NBK);
        fill_kernel<<<2048, 256, 0, stream>>>(src, dst, E, offs, bsums, gcursor, perm);
        gat_aggregate_f32_kernel<<<Nd, AGG_THREADS, 0, stream>>>(feat_src, el, er, offs,
                                                                 bsums, counts, perm, out, Nd);
    }
}